// Round 11
// baseline (1768.946 us; speedup 1.0000x reference)
//
#include <hip/hip_runtime.h>
#include <stdint.h>

// ---------------- dims ----------------
constexpr int L = 2, Bb = 2, S = 1024, H = 768, NHd = 12, HD = 64;
constexpr int E = 8, F = 3072, V = 50257;
constexpr int NTOK = Bb * S;        // 2048
constexpr int NSLOT = NTOK * 2;     // 4096 (top-2)
constexpr float EPSLN = 1e-5f;

typedef __attribute__((ext_vector_type(4))) float f32x4;
typedef __attribute__((ext_vector_type(8))) short s16x8;

#define DEVI __device__ __forceinline__

DEVI float bf2f(short u) {
  union { float f; uint32_t i; } c; c.i = ((uint32_t)(uint16_t)u) << 16; return c.f;
}
DEVI short f2bf(float f) {
  union { float f; uint32_t i; } c; c.f = f;
  uint32_t x = c.i;
  uint32_t r = (x + 0x7fffu + ((x >> 16) & 1u)) >> 16;  // RNE
  return (short)r;
}

DEVI void gload16(const void* g, void* l) {
  __builtin_amdgcn_global_load_lds(g, l, 16, 0, 0);
}

DEVI float gelu1(float g) { return 0.5f * g * (1.f + erff(g * 0.70710678118f)); }

// ---------------- small kernels ----------------
__global__ void k_f32_to_bf16(const float* __restrict__ in, short* __restrict__ out, long n4) {
  long i = (long)blockIdx.x * blockDim.x + threadIdx.x;
  if (i >= n4) return;
  long base = i * 4;
  f32x4 v = *(const f32x4*)(in + base);
  short4 o;
  o.x = f2bf(v.x); o.y = f2bf(v.y); o.z = f2bf(v.z); o.w = f2bf(v.w);
  *(short4*)(out + base) = o;
}

// in  f32 [batch][R][C]  ->  out bf16 [batch][C][R]
__global__ void k_transpose_bf16(const float* __restrict__ in, short* __restrict__ out,
                                 int R, int C, long inBS, long outBS) {
  __shared__ float tile[32][33];
  const float* src = in + (size_t)blockIdx.z * inBS;
  short* dst = out + (size_t)blockIdx.z * outBS;
  int r0 = blockIdx.y * 32, c0 = blockIdx.x * 32;
  int tx = threadIdx.x, ty = threadIdx.y;
#pragma unroll
  for (int i = 0; i < 32; i += 8) {
    int r = r0 + ty + i, c = c0 + tx;
    if (r < R && c < C) tile[ty + i][tx] = src[(size_t)r * C + c];
  }
  __syncthreads();
#pragma unroll
  for (int i = 0; i < 32; i += 8) {
    int c = c0 + ty + i, r = r0 + tx;
    if (r < R && c < C) dst[(size_t)c * R + r] = f2bf(tile[tx][ty + i]);
  }
}

// in f32 [batch][R][C] -> hi/lo bf16 [batch][C][R]
__global__ void k_transpose_split(const float* __restrict__ in, short* __restrict__ oh,
                                  short* __restrict__ ol, int R, int C, long inBS,
                                  long outBS) {
  __shared__ float tile[32][33];
  const float* src = in + (size_t)blockIdx.z * inBS;
  short* dh = oh + (size_t)blockIdx.z * outBS;
  short* dl = ol + (size_t)blockIdx.z * outBS;
  int r0 = blockIdx.y * 32, c0 = blockIdx.x * 32;
  int tx = threadIdx.x, ty = threadIdx.y;
#pragma unroll
  for (int i = 0; i < 32; i += 8) {
    int r = r0 + ty + i, c = c0 + tx;
    if (r < R && c < C) tile[ty + i][tx] = src[(size_t)r * C + c];
  }
  __syncthreads();
#pragma unroll
  for (int i = 0; i < 32; i += 8) {
    int c = c0 + ty + i, r = r0 + tx;
    if (r < R && c < C) {
      float v = tile[tx][ty + i];
      short hi = f2bf(v);
      short lo = f2bf(v - bf2f(hi));
      dh[(size_t)c * R + r] = hi;
      dl[(size_t)c * R + r] = lo;
    }
  }
}

// in f32 [R][C] -> 3-split bf16 [C][R]   (single matrix)
__global__ void k_transpose_split3(const float* __restrict__ in, short* __restrict__ o0,
                                   short* __restrict__ o1, short* __restrict__ o2,
                                   int R, int C) {
  __shared__ float tile[32][33];
  int r0 = blockIdx.y * 32, c0 = blockIdx.x * 32;
  int tx = threadIdx.x, ty = threadIdx.y;
#pragma unroll
  for (int i = 0; i < 32; i += 8) {
    int r = r0 + ty + i, c = c0 + tx;
    if (r < R && c < C) tile[ty + i][tx] = in[(size_t)r * C + c];
  }
  __syncthreads();
#pragma unroll
  for (int i = 0; i < 32; i += 8) {
    int c = c0 + ty + i, r = r0 + tx;
    if (r < R && c < C) {
      float v = tile[tx][ty + i];
      short t0 = f2bf(v);
      float rr = v - bf2f(t0);
      short t1 = f2bf(rr);
      short t2 = f2bf(rr - bf2f(t1));
      o0[(size_t)c * R + r] = t0;
      o1[(size_t)c * R + r] = t1;
      o2[(size_t)c * R + r] = t2;
    }
  }
}

// batched QKV weight transpose+split3: z=0,1,2 selects Wq/Wk/Wv (HxH each)
__global__ void k_wqkv_t3(const float* __restrict__ Wq, const float* __restrict__ Wk,
                          const float* __restrict__ Wv, short* __restrict__ o0,
                          short* __restrict__ o1, short* __restrict__ o2) {
  __shared__ float tile[32][33];
  const int zz = blockIdx.z;
  const float* in = (zz == 0) ? Wq : (zz == 1) ? Wk : Wv;
  const size_t doff = (size_t)zz * H * H;
  int r0 = blockIdx.y * 32, c0 = blockIdx.x * 32;
  int tx = threadIdx.x, ty = threadIdx.y;
#pragma unroll
  for (int i = 0; i < 32; i += 8) {
    int r = r0 + ty + i, c = c0 + tx;
    tile[ty + i][tx] = in[(size_t)r * H + c];
  }
  __syncthreads();
#pragma unroll
  for (int i = 0; i < 32; i += 8) {
    int c = c0 + ty + i, r = r0 + tx;
    float v = tile[tx][ty + i];
    short t0 = f2bf(v);
    float rr = v - bf2f(t0);
    short t1 = f2bf(rr);
    short t2 = f2bf(rr - bf2f(t1));
    o0[doff + (size_t)c * H + r] = t0;
    o1[doff + (size_t)c * H + r] = t1;
    o2[doff + (size_t)c * H + r] = t2;
  }
}

__global__ void k_bqkv(const float* __restrict__ bq, const float* __restrict__ bk,
                       const float* __restrict__ bv, float* __restrict__ bqkv) {
  int i = blockIdx.x * blockDim.x + threadIdx.x;
  if (i >= L * 3 * H) return;
  int l = i / (3 * H), j = i % (3 * H);
  float v = (j < H) ? bq[l * H + j] : (j < 2 * H) ? bk[l * H + j - H] : bv[l * H + j - 2 * H];
  bqkv[i] = v;
}

__global__ void k_ropetab(float* __restrict__ cosT, float* __restrict__ sinT) {
  int i = blockIdx.x * blockDim.x + threadIdx.x;
  if (i >= S * (HD / 2)) return;
  int s = i / 32, d = i % 32;
  float invf = powf(10000.f, -(2.f * d) / (float)HD);
  float ang = (float)s * invf;
  cosT[i] = cosf(ang);
  sinT[i] = sinf(ang);
}

__global__ void k_embed(const int* __restrict__ ids, const float* __restrict__ emb,
                        float* __restrict__ x) {
  int idx = blockIdx.x * blockDim.x + threadIdx.x;  // NTOK*(H/4)
  int row = idx / (H / 4), c4 = idx % (H / 4);
  if (row >= NTOK) return;
  int t = ids[row];
  ((f32x4*)(x + (size_t)row * H))[c4] = ((const f32x4*)(emb + (size_t)t * H))[c4];
}

// ---------------- layernorm with fused output formats ----------------
// OUT 1: split3 -> s0,s1,s2        OUT 2: f32 of + split2 -> s0,s1
// OUT 3: f32 of + bf16 -> s0       OUT 4: bf16 -> s0
template <int OUT>
__global__ void k_layernorm(const float* __restrict__ x, const float* __restrict__ w,
                            const float* __restrict__ b, float* __restrict__ of,
                            short* __restrict__ s0, short* __restrict__ s1,
                            short* __restrict__ s2) {
  int row = blockIdx.x * (blockDim.x >> 6) + (threadIdx.x >> 6);
  int lane = threadIdx.x & 63;
  if (row >= NTOK) return;
  const float* xr = x + (size_t)row * H;
  float v[12], s = 0.f, s2s = 0.f;
#pragma unroll
  for (int j = 0; j < 12; j++) { float t = xr[lane + j * 64]; v[j] = t; s += t; s2s += t * t; }
#pragma unroll
  for (int off = 32; off; off >>= 1) { s += __shfl_xor(s, off); s2s += __shfl_xor(s2s, off); }
  float m = s / (float)H;
  float var = s2s / (float)H - m * m;
  float rs = 1.f / sqrtf(var + EPSLN);
#pragma unroll
  for (int j = 0; j < 12; j++) {
    int c = lane + j * 64;
    float val = (v[j] - m) * rs * w[c] + b[c];
    size_t idx = (size_t)row * H + c;
    if (OUT == 1) {
      short t0 = f2bf(val);
      float rr = val - bf2f(t0);
      short t1 = f2bf(rr);
      short t2 = f2bf(rr - bf2f(t1));
      s0[idx] = t0; s1[idx] = t1; s2[idx] = t2;
    } else if (OUT == 2) {
      of[idx] = val;
      short hi = f2bf(val);
      s0[idx] = hi; s1[idx] = f2bf(val - bf2f(hi));
    } else if (OUT == 3) {
      of[idx] = val;
      s0[idx] = f2bf(val);
    } else {
      s0[idx] = f2bf(val);
    }
  }
}

// ---------------- softmax over hi/lo bf16 scores, in place -------------------
__global__ void k_softmax2(short* __restrict__ p0, short* __restrict__ p1) {
  int row = blockIdx.x * 4 + (threadIdx.x >> 6);  // B*NH*S rows
  int lane = threadIdx.x & 63;
  s16x8* r0 = (s16x8*)(p0 + (size_t)row * S + lane * 16);
  s16x8* r1 = (s16x8*)(p1 + (size_t)row * S + lane * 16);
  s16x8 h0 = r0[0], h1 = r0[1];
  s16x8 l0 = r1[0], l1 = r1[1];
  float v[16];
#pragma unroll
  for (int j = 0; j < 8; j++) {
    v[j] = bf2f(h0[j]) + bf2f(l0[j]);
    v[8 + j] = bf2f(h1[j]) + bf2f(l1[j]);
  }
  float mx = -3e38f;
#pragma unroll
  for (int j = 0; j < 16; j++) mx = fmaxf(mx, v[j]);
#pragma unroll
  for (int off = 32; off; off >>= 1) mx = fmaxf(mx, __shfl_xor(mx, off));
  float sum = 0.f;
#pragma unroll
  for (int j = 0; j < 16; j++) { v[j] = expf(v[j] - mx); sum += v[j]; }
#pragma unroll
  for (int off = 32; off; off >>= 1) sum += __shfl_xor(sum, off);
  float inv = 1.f / sum;
#pragma unroll
  for (int j = 0; j < 16; j++) v[j] *= inv;
  s16x8 oh0, oh1, ol0, ol1;
#pragma unroll
  for (int j = 0; j < 8; j++) {
    short hi = f2bf(v[j]);
    oh0[j] = hi; ol0[j] = f2bf(v[j] - bf2f(hi));
    short hi2 = f2bf(v[8 + j]);
    oh1[j] = hi2; ol1[j] = f2bf(v[8 + j] - bf2f(hi2));
  }
  r0[0] = oh0; r0[1] = oh1;
  r1[0] = ol0; r1[1] = ol1;
}

// ---------------- router (f32 h input -> exact top-2) ----------------
__global__ void k_router(const float* __restrict__ h, const float* __restrict__ Wr,
                         const float* __restrict__ br, float* __restrict__ sel_w,
                         int* __restrict__ sel_e, int* __restrict__ counts) {
  int tok = blockIdx.x * (blockDim.x >> 6) + (threadIdx.x >> 6);
  int lane = threadIdx.x & 63;
  if (tok >= NTOK) return;
  const float* hr = h + (size_t)tok * H;
  float acc[8] = {0, 0, 0, 0, 0, 0, 0, 0};
  for (int i = lane; i < H; i += 64) {
    float hv = hr[i];
    const f32x4* w4 = (const f32x4*)(Wr + (size_t)i * E);
    f32x4 a = w4[0], b = w4[1];
    acc[0] += hv * a.x; acc[1] += hv * a.y; acc[2] += hv * a.z; acc[3] += hv * a.w;
    acc[4] += hv * b.x; acc[5] += hv * b.y; acc[6] += hv * b.z; acc[7] += hv * b.w;
  }
#pragma unroll
  for (int off = 32; off; off >>= 1)
#pragma unroll
    for (int e = 0; e < 8; e++) acc[e] += __shfl_xor(acc[e], off);
  if (lane == 0) {
    float lg[8], m = -3e38f;
#pragma unroll
    for (int e = 0; e < 8; e++) { lg[e] = acc[e] + br[e]; m = fmaxf(m, lg[e]); }
    float sum = 0.f;
#pragma unroll
    for (int e = 0; e < 8; e++) { lg[e] = expf(lg[e] - m); sum += lg[e]; }
    float inv = 1.f / sum;
#pragma unroll
    for (int e = 0; e < 8; e++) lg[e] *= inv;
    int i1 = 0;
#pragma unroll
    for (int e = 1; e < 8; e++) if (lg[e] > lg[i1]) i1 = e;
    int i2 = (i1 == 0) ? 1 : 0;
#pragma unroll
    for (int e = 0; e < 8; e++) if (e != i1 && lg[e] > lg[i2]) i2 = e;
    float p1 = lg[i1], p2 = lg[i2];
    float ws = p1 + p2 + 1e-9f;
    sel_e[tok * 2] = i1; sel_e[tok * 2 + 1] = i2;
    sel_w[tok * 2] = p1 / ws; sel_w[tok * 2 + 1] = p2 / ws;
    atomicAdd(counts + i1, 1);
    atomicAdd(counts + i2, 1);
  }
}

__global__ void k_offsets(const int* __restrict__ counts, int* __restrict__ offs) {
  if (threadIdx.x == 0) {
    int a = 0;
    for (int e = 0; e < E; e++) { offs[e] = a; a += counts[e]; }
    offs[E] = a;
  }
}

__global__ void k_scatter(const int* __restrict__ sel_e, const int* __restrict__ offs,
                          int* __restrict__ cursor, int* __restrict__ tok_list,
                          int* __restrict__ slot_of) {
  int tok = blockIdx.x * blockDim.x + threadIdx.x;
  if (tok >= NTOK) return;
  for (int k = 0; k < 2; k++) {
    int e = sel_e[tok * 2 + k];
    int pos = atomicAdd(cursor + e, 1);
    int g = offs[e] + pos;
    tok_list[g] = tok;
    slot_of[tok * 2 + k] = g;
  }
}

// ff = sum_k w_k * (oe[slot_k] + b2[e_k]); x += ff
__global__ void k_combine(const float* __restrict__ oe, const float* __restrict__ sel_w,
                          const int* __restrict__ slot_of, const int* __restrict__ sel_e,
                          const float* __restrict__ b2, float* __restrict__ x) {
  int idx = blockIdx.x * blockDim.x + threadIdx.x;  // NTOK*(H/4)
  if (idx >= NTOK * (H / 4)) return;
  int tok = idx / (H / 4), c4 = idx % (H / 4);
  float w0 = sel_w[tok * 2], w1 = sel_w[tok * 2 + 1];
  int s0 = slot_of[tok * 2], s1 = slot_of[tok * 2 + 1];
  int e0 = sel_e[tok * 2], e1 = sel_e[tok * 2 + 1];
  f32x4 a = ((const f32x4*)(oe + (size_t)s0 * H))[c4];
  f32x4 b = ((const f32x4*)(oe + (size_t)s1 * H))[c4];
  f32x4 ba = ((const f32x4*)(b2 + (size_t)e0 * H))[c4];
  f32x4 bb = ((const f32x4*)(b2 + (size_t)e1 * H))[c4];
  f32x4* xp = (f32x4*)(x + (size_t)tok * H) + c4;
  *xp = *xp + w0 * (a + ba) + w1 * (b + bb);
}

// ---------------- split-MFMA GEMM: C = (ΣA_s)·(ΣB_s)^T, products i+j<SP -----
// SP=2: 3 MFMAs/frag; SP=3: 6 MFMAs/frag.
// MODE 0: f32 out (+bias opt)   1: f32 out = res + acc + bias
// MODE 6: gelu(acc+bias) -> split2 bf16 (Cp,Cp2)
// MODE 7: acc*alpha + causal -> split2 bf16 (Cp,Cp2)
// MODE 8: acc -> split3 bf16 (Cp,Cp2,Cp3)
// MODE 9: QKV fused: bias + RoPE + split3(q->Cp..3, k->K0..2) / split2(v->V0,V1)
template <int SP, int MODE, bool GATHER>
__global__ __launch_bounds__(256, 2) void k_bgemmS(
    const short* __restrict__ A0, const short* __restrict__ A1, const short* __restrict__ A2,
    long sAz, int lda,
    const short* __restrict__ B0, const short* __restrict__ B1, const short* __restrict__ B2,
    long sBz, int ldb,
    void* __restrict__ Cp, void* __restrict__ Cp2, void* __restrict__ Cp3,
    short* __restrict__ K0, short* __restrict__ K1, short* __restrict__ K2,
    short* __restrict__ V0, short* __restrict__ V1,
    const float* __restrict__ cT, const float* __restrict__ sT,
    int zdiv, long sChi, long sClo, int ldc,
    const float* __restrict__ res, const float* __restrict__ bias, long sBias,
    int M, int N, int K,
    const int* __restrict__ d_counts, const int* __restrict__ d_offs,
    const int* __restrict__ gidx, float alpha) {
  const int z = blockIdx.z;
  const int Meff = d_counts ? d_counts[z] : M;
  const int tm = blockIdx.y;
  if (tm * 128 >= Meff) return;
  const int tn = blockIdx.x;
  const int row_base = d_offs ? d_offs[z] : 0;

  __shared__ short Ab[SP][128 * 32];
  __shared__ short Bb2[SP][128 * 32];

  const int tid = threadIdx.x;
  const int lane = tid & 63;
  const int w = tid >> 6;

  const short* APz[3];
  const short* BPz[3];
  APz[0] = A0 + (size_t)z * sAz;
  APz[1] = A1 + (size_t)z * sAz;
  APz[2] = (SP > 2) ? (A2 + (size_t)z * sAz) : APz[0];
  BPz[0] = B0 + (size_t)z * sBz;
  BPz[1] = B1 + (size_t)z * sBz;
  BPz[2] = (SP > 2) ? (B2 + (size_t)z * sBz) : BPz[0];

  size_t aOff[2], bOff[2];
#pragma unroll
  for (int i = 0; i < 2; ++i) {
    const int srow = i * 64 + (tid >> 2);
    const int kb = (tid & 3) ^ (srow & 3);  // pre-swizzled source (involution)
    int lrow = tm * 128 + srow;
    if (lrow > Meff - 1) lrow = Meff - 1;
    int ar = row_base + lrow;
    if (GATHER) ar = gidx[ar];
    aOff[i] = (size_t)ar * lda + kb * 8;
    int bcol = tn * 128 + srow;
    if (bcol > N - 1) bcol = N - 1;
    bOff[i] = (size_t)bcol * ldb + kb * 8;
  }

  f32x4 acc[4][4];
#pragma unroll
  for (int a = 0; a < 4; ++a)
#pragma unroll
    for (int b = 0; b < 4; ++b) acc[a][b] = {0.f, 0.f, 0.f, 0.f};

  const int wr = (w >> 1) * 64;
  const int wc = (w & 1) * 64;
  const int r16 = lane & 15;
  const int kb4 = lane >> 4;
  const int swz = (kb4 ^ (r16 & 3)) * 8;
  int aoff[4], boff[4];
#pragma unroll
  for (int i = 0; i < 4; ++i) {
    aoff[i] = (wr + i * 16 + r16) * 32 + swz;
    boff[i] = (wc + i * 16 + r16) * 32 + swz;
  }

  for (int k0 = 0; k0 < K; k0 += 32) {
#pragma unroll
    for (int s = 0; s < SP; ++s) {
      gload16(APz[s] + aOff[0], (char*)(&Ab[s][0]) + w * 1024);
      gload16(APz[s] + aOff[1], (char*)(&Ab[s][0]) + 4096 + w * 1024);
      gload16(BPz[s] + bOff[0], (char*)(&Bb2[s][0]) + w * 1024);
      gload16(BPz[s] + bOff[1], (char*)(&Bb2[s][0]) + 4096 + w * 1024);
    }
    aOff[0] += 32; aOff[1] += 32; bOff[0] += 32; bOff[1] += 32;
    __syncthreads();
    s16x8 af[SP][4], bf[SP][4];
#pragma unroll
    for (int s = 0; s < SP; ++s)
#pragma unroll
      for (int i = 0; i < 4; ++i) {
        af[s][i] = *(const s16x8*)(&Ab[s][aoff[i]]);
        bf[s][i] = *(const s16x8*)(&Bb2[s][boff[i]]);
      }
#pragma unroll
    for (int mi = 0; mi < 4; ++mi)
#pragma unroll
      for (int ni = 0; ni < 4; ++ni) {
        f32x4 a = acc[mi][ni];
#pragma unroll
        for (int si = 0; si < SP; ++si)
#pragma unroll
          for (int sj = 0; sj < SP - si; ++sj)
            a = __builtin_amdgcn_mfma_f32_16x16x32_bf16(af[si][mi], bf[sj][ni], a, 0, 0, 0);
        acc[mi][ni] = a;
      }
    __syncthreads();
  }

  const float* bz = bias ? (bias + (size_t)z * sBias) : nullptr;
  const int q4 = lane >> 4;
  float bvv[4];
  int gco[4];
#pragma unroll
  for (int ni = 0; ni < 4; ++ni) {
    gco[ni] = tn * 128 + wc + ni * 16 + r16;
    bvv[ni] = (bz && gco[ni] < N) ? bz[gco[ni]] : 0.f;
  }

  if (MODE == 9) {
    // QKV fused epilogue: cols = [q(768) | k(768) | v(768)], heads of 64.
    const int sec_base = tn * 128 + wc;     // multiple of 64, aligned to sections
    const int sec = sec_base / H;           // 0=q, 1=k, 2=v
    const int hh = (sec_base % H) / HD;
#pragma unroll
    for (int mi = 0; mi < 4; ++mi) {
#pragma unroll
      for (int j = 0; j < 4; ++j) {
        const int row = tm * 128 + wr + mi * 16 + q4 * 4 + j;   // token
        const int ss = row & (S - 1);
        const long zz = (long)((row >> 10) * NHd + hh);
#pragma unroll
        for (int ni = 0; ni < 2; ++ni) {
          const int d = ni * 16 + r16;                          // 0..31
          float a1 = acc[mi][ni][j] + bvv[ni];
          float a2 = acc[mi][ni + 2][j] + bvv[ni + 2];
          if (sec < 2) {
            float cc = cT[ss * 32 + d], sn = sT[ss * 32 + d];
            float r1 = a1 * cc - a2 * sn;
            float r2 = a2 * cc + a1 * sn;
            const long bi = (zz * S + ss) * HD + d;
            short* d0 = (sec == 0) ? (short*)Cp : K0;
            short* d1 = (sec == 0) ? (short*)Cp2 : K1;
            short* d2 = (sec == 0) ? (short*)Cp3 : K2;
            short t0 = f2bf(r1); float rr = r1 - bf2f(t0);
            short t1 = f2bf(rr); short t2 = f2bf(rr - bf2f(t1));
            d0[bi] = t0; d1[bi] = t1; d2[bi] = t2;
            t0 = f2bf(r2); rr = r2 - bf2f(t0);
            t1 = f2bf(rr); t2 = f2bf(rr - bf2f(t1));
            d0[bi + 32] = t0; d1[bi + 32] = t1; d2[bi + 32] = t2;
          } else {
            const long vb1 = zz * HD * S + (long)d * S + ss;
            short hv = f2bf(a1);
            V0[vb1] = hv; V1[vb1] = f2bf(a1 - bf2f(hv));
            const long vb2 = vb1 + 32L * S;
            hv = f2bf(a2);
            V0[vb2] = hv; V1[vb2] = f2bf(a2 - bf2f(hv));
          }
        }
      }
    }
    return;
  }

  const long out_off = (long)(z / zdiv) * sChi + (long)(z % zdiv) * sClo;
#pragma unroll
  for (int mi = 0; mi < 4; ++mi) {
#pragma unroll
    for (int j = 0; j < 4; ++j) {
      const int lrow = tm * 128 + wr + mi * 16 + q4 * 4 + j;
      if (lrow >= Meff) continue;
      const long rbase = out_off + (long)(row_base + lrow) * ldc;
#pragma unroll
      for (int ni = 0; ni < 4; ++ni) {
        if (gco[ni] >= N) continue;
        const float v = acc[mi][ni][j];
        const long idx = rbase + gco[ni];
        if (MODE == 0) {
          ((float*)Cp)[idx] = v + bvv[ni];
        } else if (MODE == 1) {
          ((float*)Cp)[idx] = res[idx] + v + bvv[ni];
        } else if (MODE == 6) {
          float g = gelu1(v + bvv[ni]);
          short hi = f2bf(g);
          ((short*)Cp)[idx] = hi;
          ((short*)Cp2)[idx] = f2bf(g - bf2f(hi));
        } else if (MODE == 7) {
          float g = v * alpha + ((gco[ni] > lrow) ? -1e9f : 0.f);
          short hi = f2bf(g);
          ((short*)Cp)[idx] = hi;
          ((short*)Cp2)[idx] = f2bf(g - bf2f(hi));
        } else if (MODE == 8) {
          float g = v + bvv[ni];
          short t0 = f2bf(g); float rr = g - bf2f(t0);
          short t1 = f2bf(rr); short t2 = f2bf(rr - bf2f(t1));
          ((short*)Cp)[idx] = t0;
          ((short*)Cp2)[idx] = t1;
          ((short*)Cp3)[idx] = t2;
        }
      }
    }
  }
}

template <int SP, int MODE, bool GATHER>
static void bgemmS(hipStream_t st, const short* A0, const short* A1, const short* A2, long sAz,
                   int lda, const short* B0, const short* B1, const short* B2, long sBz,
                   int ldb, void* C, void* C2, void* C3, int zdiv, long sChi, long sClo,
                   int ldc, const float* res, const float* bias, long sBias, int M, int N,
                   int K, int nz, const int* cnts, const int* offs_, const int* gat,
                   float alpha, short* K0 = nullptr, short* K1 = nullptr, short* K2 = nullptr,
                   short* V0 = nullptr, short* V1 = nullptr, const float* cT = nullptr,
                   const float* sT = nullptr) {
  dim3 g((N + 127) / 128, (M + 127) / 128, nz);
  k_bgemmS<SP, MODE, GATHER><<<g, 256, 0, st>>>(A0, A1, A2, sAz, lda, B0, B1, B2, sBz, ldb, C,
                                                C2, C3, K0, K1, K2, V0, V1, cT, sT, zdiv, sChi,
                                                sClo, ldc, res, bias, sBias, M, N, K, cnts,
                                                offs_, gat, alpha);
}

// ------- plain bf16 MFMA GEMM, 256x128 tile, BK=64 (l1 MoE + logits) --------
// Each wave owns 64 rows x 128 cols: acc[4][8]. Same ascending-K accumulation
// order as the 128-tile BK=64 version (bit-identical results).
// MODE 0: f32 out (+bias opt)   4: bf16 out = gelu(acc + bias)
// NSWZ: N-major + bijective XCD-chunk swizzle (B-tile L2 locality).
template <int MODE, bool GATHER, bool NSWZ>
__global__ __launch_bounds__(256, 2) void k_bgemm(
    const short* __restrict__ A, long sAz, int lda,
    const short* __restrict__ Bt, long sBz, int ldb,
    void* __restrict__ Cp, int zdiv, long sChi, long sClo, int ldc,
    const float* __restrict__ bias, long sBias,
    int M, int N, int K,
    const int* __restrict__ d_counts, const int* __restrict__ d_offs,
    const int* __restrict__ gidx) {
  const int z = blockIdx.z;
  const int Meff = d_counts ? d_counts[z] : M;
  int tm, tn;
  if (NSWZ) {
    const int bid = blockIdx.y * gridDim.x + blockIdx.x;
    const int nwg = gridDim.x * gridDim.y;
    const int q = nwg >> 3, r = nwg & 7;
    const int xcd = bid & 7, ix = bid >> 3;
    const int wg = (xcd < r) ? (xcd * (q + 1) + ix) : (r * (q + 1) + (xcd - r) * q + ix);
    tn = wg / gridDim.y;   // N-major: consecutive wg share tn
    tm = wg % gridDim.y;
  } else {
    tm = blockIdx.y;
    tn = blockIdx.x;
  }
  if (tm * 256 >= Meff) return;
  const int row_base = d_offs ? d_offs[z] : 0;

  __shared__ short Abuf[256 * 64];   // 32 KB
  __shared__ short Bbuf[128 * 64];   // 16 KB

  const int tid = threadIdx.x;
  const int lane = tid & 63;
  const int w = tid >> 6;

  const short* Az = A + (size_t)z * sAz;
  const short* Bz = Bt + (size_t)z * sBz;

  // staging: A chunk c=w*8+i covers LDS rows c*8..c*8+7 (8 loads/thread);
  // B chunk c=w*4+i (4 loads/thread). lane -> row c*8+(lane>>3), k-unit lane&7;
  // source k pre-swizzled by (row&7)^unit (involution, both-sides).
  const int swzS = ((lane >> 3) ^ (lane & 7)) * 8;
  const short* aSrc[8];
  const short* bSrc[4];
#pragma unroll
  for (int i = 0; i < 8; ++i) {
    const int rin = (w * 8 + i) * 8 + (lane >> 3);  // 0..255
    int lrow = tm * 256 + rin;
    if (lrow > Meff - 1) lrow = Meff - 1;
    int ar = row_base + lrow;
    if (GATHER) ar = gidx[ar];
    aSrc[i] = Az + (size_t)ar * lda + swzS;
  }
#pragma unroll
  for (int i = 0; i < 4; ++i) {
    const int rin = (w * 4 + i) * 8 + (lane >> 3);  // 0..127
    int bcol = tn * 128 + rin;
    if (bcol > N - 1) bcol = N - 1;
    bSrc[i] = Bz + (size_t)bcol * ldb + swzS;
  }

  f32x4 acc[4][8];
#pragma unroll
  for (int a = 0; a < 4; ++a)
#pragma unroll
    for (int b = 0; b < 8; ++b) acc[a][b] = {0.f, 0.f, 0.f, 0.f};

  const int r16 = lane & 15;
  const int kb4 = lane >> 4;
  int aoff[4][2], boff[8][2];
#pragma unroll
  for (int kw = 0; kw < 2; ++kw) {
    const int sw = ((r16 & 7) ^ (kw * 4 + kb4)) * 8;
#pragma unroll
    for (int i = 0; i < 4; ++i) aoff[i][kw] = (w * 64 + i * 16 + r16) * 64 + sw;
#pragma unroll
    for (int i = 0; i < 8; ++i) boff[i][kw] = (i * 16 + r16) * 64 + sw;
  }

  for (int k0 = 0; k0 < K; k0 += 64) {
#pragma unroll
    for (int i = 0; i < 8; ++i) gload16(aSrc[i], (char*)Abuf + (w * 8 + i) * 1024);
#pragma unroll
    for (int i = 0; i < 4; ++i) gload16(bSrc[i], (char*)Bbuf + (w * 4 + i) * 1024);
#pragma unroll
    for (int i = 0; i < 8; ++i) aSrc[i] += 64;
#pragma unroll
    for (int i = 0; i < 4; ++i) bSrc[i] += 64;
    __syncthreads();
#pragma unroll
    for (int kw = 0; kw < 2; ++kw) {
      s16x8 af[4], bf[8];
#pragma unroll
      for (int i = 0; i < 4; ++i) af[i] = *(const s16x8*)(Abuf + aoff[i][kw]);
#pragma unroll
      for (int i = 0; i < 8; ++i) bf[i] = *(const s16x8*)(Bbuf + boff[i][kw]);
#pragma unroll
      for (int mi = 0; mi < 4; ++mi)
#pragma unroll
        for (int ni = 0; ni < 8; ++ni)
          acc[mi][ni] =
              __builtin_amdgcn_mfma_f32_16x16x32_bf16(af[mi], bf[ni], acc[mi][ni], 0, 0, 0);
    }
    __syncthreads();
  }

  const long out_off = (long)(z / zdiv) * sChi + (long)(z % zdiv) * sClo;
  const float* bz = bias ? (bias + (size_t)z * sBias) : nullptr;
  const int q4 = lane >> 4;
  float bvv[8];
  int gco[8];
#pragma unroll
  for (int ni = 0; ni < 8; ++ni) {
    gco[ni] = tn * 128 + ni * 16 + r16;
    bvv[ni] = (bz && gco[ni] < N) ? bz[gco[ni]] : 0.f;
  }
#pragma unroll
  for (int mi = 0; mi < 4; ++mi) {
#pragma unroll
    for (int j = 0; j < 4; ++j) {
      const int lrow = tm * 256 + w * 64 + mi * 16 + q4 * 4 + j;
      if (lrow >= Meff) continue;
      const long rbase = out_off + (row_base + lrow) * (long)ldc;
#pragma unroll
      for (int ni = 0; ni < 8; ++ni) {
        if (gco[ni] >= N) continue;
        const float v = acc[mi][ni][j];
        if (MODE == 0) {
          ((float*)Cp)[rbase + gco[ni]] = v + bvv[ni];
        } else if (MODE == 4) {
          float g = v + bvv[ni];
          ((short*)Cp)[rbase + gco[ni]] = f2bf(gelu1(g));
        }
      }
    }
  }
}

template <int MODE, bool GATHER, bool NSWZ>
static void bgemm(hipStream_t st, const short* A, long sAz, int lda, const short* Bt, long sBz,
                  int ldb, void* C, int zdiv, long sChi, long sClo, int ldc, const float* bias,
                  long sBias, int M, int N, int K, int nz, const int* cnts, const int* offs_,
                  const int* gat) {
  dim3 g((N + 127) / 128, (M + 255) / 256, nz);
  k_bgemm<MODE, GATHER, NSWZ><<<g, 256, 0, st>>>(A, sAz, lda, Bt, sBz, ldb, C, zdiv, sChi,
                                                 sClo, ldc, bias, sBias, M, N, K, cnts, offs_,
                                                 gat);
}

// ---------------- launch ----------------
extern "C" void kernel_launch(void* const* d_in, const int* in_sizes, int n_in, void* d_out,
                              int out_size, void* d_ws, size_t ws_size, hipStream_t stream) {
  (void)in_sizes; (void)n_in; (void)out_size; (void)ws_size;
  const int*   ids  = (const int*)d_in[0];
  const float* emb  = (const float*)d_in[1];
  const float* ln1w = (const float*)d_in[2];
  const float* ln1b = (const float*)d_in[3];
  const float* ln2w = (const float*)d_in[4];
  const float* ln2b = (const float*)d_in[5];
  const float* lnfw = (const float*)d_in[6];
  const float* lnfb = (const float*)d_in[7];
  const float* Wq = (const float*)d_in[8];
  const float* bq = (const float*)d_in[9];
  const float* Wk = (const float*)d_in[10];
  const float* bk = (const float*)d_in[11];
  const float* Wv = (const float*)d_in[12];
  const float* bv = (const float*)d_in[13];
  const float* Wo = (const float*)d_in[14];
  const float* bo = (const float*)d_in[15];
  const float* Wr = (const float*)d_in[16];
  const float* br = (const float*)d_in[17];
  const float* W1 = (const float*)d_in[18];
  const float* b1 = (const float*)d_in[19];
  const float* W2 = (const float*)d_in[20];
  const float* b2 = (const float*)d_in[21];
  float* out = (float*)d_out;

  char* p = (char*)d_ws;
  auto alloc = [&](size_t bytes) {
    char* r = p;
    p += (bytes + 255) & ~(size_t)255;
    return r;
  };
  short* embB = (short*)alloc((size_t)V * H * 2);               // 77.2 MB
  // big region (100.7 MB), time-shared: attention [p0|p1] vs MoE [R_hi|R_lo]
  char* big = alloc((size_t)Bb * NHd * S * S * 2 * 2);
  short* p0   = (short*)big;
  short* p1   = p0 + (size_t)Bb * NHd * S * S;
  short* R_hi = (short*)big;
  short* R_lo = R_hi + (size_t)E * F * H;
  short* Wb0 = (short*)alloc((size_t)3 * H * H * 2);            // QKV W^T 3-splits
  short* Wb1 = (short*)alloc((size_t)3 * H * H * 2);
  short* Wb2 = (short*)alloc((size_t)3 * H * H * 2);
  short* Wo0 = (short*)alloc((size_t)H * H * 2);                // Wo^T 3-splits
  short* Wo1 = (short*)alloc((size_t)H * H * 2);
  short* Wo2 = (short*)alloc((size_t)H * H * 2);
  float* bqkv = (float*)alloc((size_t)L * 3 * H * 4);
  float* cosT = (float*)alloc((size_t)S * 32 * 4);
  float* sinT = (float*)alloc((size_t)S * 32 * 4);
  float* x    = (float*)alloc((size_t)NTOK * H * 4);
  float* hbuf = (float*)alloc((size_t)NTOK * H * 4);
  short* xb   = (short*)alloc((size_t)NTOK * H * 2);
  short* xb2  = (short*)alloc((size_t)NTOK * H * 2);
  short* h_hi = (short*)alloc((size_t)NTOK * H * 2);
  short* h_lo = (short*)alloc((size_t)NTOK * H * 2);
  short* h30  = (short*)alloc((size_t)NTOK * H * 2);
  short* h31  = (short*)alloc((size_t)NTOK * H * 2);
  short* h32  = (short*)alloc((size_t)NTOK * H * 2);
  short* q30  = (short*)alloc((size_t)NTOK * H * 2);
  short* q31  = (short*)alloc((size_t)NTOK * H * 2);
  short* q32  = (short*)alloc((size_t)NTOK * H * 2);
  short* k30  = (short*)alloc((size_t)NTOK * H * 2);
  short* k31  = (short*)alloc((size_t)NTOK * H * 2);
  short* k32  = (short*)alloc((size_t)NTOK * H * 2);
  short* v20  = (short*)alloc((size_t)NTOK * H * 2);
  short* v21  = (short*)alloc((size_t)NTOK * H * 2);
  short* o30  = (short*)alloc((size_t)NTOK * H * 2);
  short* o31  = (short*)alloc((size_t)NTOK * H * 2);
  short* o32  = (short*)alloc((size_t)NTOK * H * 2);
  // union region (63.1 MB): act_hi+act_lo (l0) / act_b (l1) + oe
  char* uni = alloc((size_t)NSLOT * F * 4 + (size_t)NSLOT * H * 4);
  short* act_hi = (short*)uni;
  short* act_lo = (short*)(uni + (size_t)NSLOT * F * 2);
  short* act_b  = (short*)uni;
  float* oe     = (float*)(uni + (size_t)NSLOT * F * 4);
  int* counts  = (int*)alloc(2 * E * 4);
  int* cursor  = counts + E;
  int* offs    = (int*)alloc((E + 1) * 4);
  int* sel_e   = (int*)alloc((size_t)NTOK * 2 * 4);
  float* sel_w = (float*)alloc((size_t)NTOK * 2 * 4);
  int* slot_of = (int*)alloc((size_t)NTOK * 2 * 4);
  int* tok_lst = (int*)alloc((size_t)NSLOT * 4);

  // ---- prologue ----
  long nEmb4 = (long)V * H / 4;
  k_f32_to_bf16<<<(nEmb4 + 255) / 256, 256, 0, stream>>>(emb, embB, nEmb4);
  k_bqkv<<<(L * 3 * H + 255) / 256, 256, 0, stream>>>(bq, bk, bv, bqkv);
  k_ropetab<<<(S * 32 + 255) / 256, 256, 0, stream>>>(cosT, sinT);
  k_embed<<<(NTOK * (H / 4) + 255) / 256, 256, 0, stream>>>(ids, emb, x);

  dim3 tb(32, 8);
  const dim3 tHH(H / 32, H / 32, 1);

  for (int l = 0; l < L; l++) {
    // --- attention (bf16x6 split-MFMA; upstream of routers) ---
    k_layernorm<1><<<NTOK / 4, 256, 0, stream>>>(x, ln1w + l * H, ln1b + l * H, nullptr, h30,
                                                 h31, h32);
    k_wqkv_t3<<<dim3(H / 32, H / 32, 3), tb, 0, stream>>>(
        Wq + (size_t)l * H * H, Wk + (size_t)l * H * H, Wv + (size_t)l * H * H, Wb0, Wb1, Wb2);
    // QKV fused with bias+RoPE+splits (MODE 9)
    bgemmS<3, 9, false>(stream, h30, h31, h32, 0, H, Wb0, Wb1, Wb2, 0, H, q30, q31, q32, 1, 0,
                        0, 0, nullptr, bqkv + l * 3 * H, 0, NTOK, 3 * H, H, 1, nullptr,
                        nullptr, nullptr, 1.f, k30, k31, k32, v20, v21, cosT, sinT);
    // QK^T: scale+causal -> hi/lo bf16 scores
    bgemmS<3, 7, false>(stream, q30, q31, q32, (long)S * HD, HD, k30, k31, k32, (long)S * HD,
                        HD, p0, p1, nullptr, 1, (long)S * S, 0, S, nullptr, nullptr, 0, S, S,
                        HD, Bb * NHd, nullptr, nullptr, nullptr, 0.125f);
    k_softmax2<<<(Bb * NHd * S) / 4, 256, 0, stream>>>(p0, p1);
    // PV -> o split3 (MODE 8)
    bgemmS<2, 8, false>(stream, p0, p1, nullptr, (long)S * S, S, v20, v21, nullptr,
                        (long)HD * S, S, o30, o31, o32, NHd, (long)S * H, HD, H, nullptr,
                        nullptr, 0, S, HD, S, Bb * NHd, nullptr, nullptr, nullptr, 1.f);
    // Wo: x += o @ Wo + bo
    k_transpose_split3<<<tHH, tb, 0, stream>>>(Wo + (size_t)l * H * H, Wo0, Wo1, Wo2, H, H);
    bgemmS<3, 1, false>(stream, o30, o31, o32, 0, H, Wo0, Wo1, Wo2, 0, H, x, nullptr, nullptr,
                        1, 0, 0, H, x, bo + l * H, 0, NTOK, H, H, 1, nullptr, nullptr, nullptr,
                        1.f);

    // --- MoE ---
    if (l == 0)
      k_layernorm<2><<<NTOK / 4, 256, 0, stream>>>(x, ln2w + l * H, ln2b + l * H, hbuf, h_hi,
                                                   h_lo, nullptr);
    else
      k_layernorm<3><<<NTOK / 4, 256, 0, stream>>>(x, ln2w + l * H, ln2b + l * H, hbuf, xb2,
                                                   nullptr, nullptr);
    hipMemsetAsync(counts, 0, 2 * E * sizeof(int), stream);
    k_router<<<NTOK / 4, 256, 0, stream>>>(hbuf, Wr + (size_t)l * H * E, br + l * E, sel_w,
                                           sel_e, counts);
    k_offsets<<<1, 64, 0, stream>>>(counts, offs);
    k_scatter<<<(NTOK + 255) / 256, 256, 0, stream>>>(sel_e, offs, cursor, tok_lst, slot_of);
    if (l == 0) {
      // bf16x3 split MFMA experts (proven path; p0/p1 dead -> R region free)
      k_transpose_split<<<dim3(F / 32, H / 32, E), tb, 0, stream>>>(
          W1, R_hi, R_lo, H, F, (long)H * F, (long)F * H);
      bgemmS<2, 6, true>(stream, h_hi, h_lo, nullptr, 0, H, R_hi, R_lo, nullptr, (long)F * H,
                         H, act_hi, act_lo, nullptr, 1, 0, 0, F, nullptr, b1, F, NSLOT, F, H,
                         E, counts, offs, tok_lst, 1.f);
      k_transpose_split<<<dim3(H / 32, F / 32, E), tb, 0, stream>>>(
          W2, R_hi, R_lo, F, H, (long)F * H, (long)H * F);
      bgemmS<2, 0, false>(stream, act_hi, act_lo, nullptr, 0, F, R_hi, R_lo, nullptr,
                          (long)H * F, F, oe, nullptr, nullptr, 1, 0, 0, H, nullptr, nullptr,
                          0, NSLOT, H, F, E, counts, offs, nullptr, 1.f);
      k_combine<<<(NTOK * (H / 4) + 255) / 256, 256, 0, stream>>>(oe, sel_w, slot_of, sel_e,
                                                                  b2, x);
    } else {
      // plain bf16 MFMA experts (256-tile BK=64); stage l1 weights
      k_transpose_bf16<<<dim3(F / 32, H / 32, E), tb, 0, stream>>>(
          W1 + (size_t)1 * E * H * F, R_hi, H, F, (long)H * F, (long)F * H);
      k_transpose_bf16<<<dim3(H / 32, F / 32, E), tb, 0, stream>>>(
          W2 + (size_t)1 * E * F * H, R_lo, F, H, (long)F * H, (long)H * F);
      bgemm<4, true, false>(stream, xb2, 0, H, R_hi, (long)F * H, H, act_b, 1, 0, 0, F,
                            b1 + (size_t)l * E * F, F, NSLOT, F, H, E, counts, offs, tok_lst);
      bgemm<0, false, false>(stream, act_b, 0, F, R_lo, (long)H * F, F, oe, 1, 0, 0, H,
                             nullptr, 0, NSLOT, H, F, E, counts, offs, nullptr);
      k_combine<<<(NTOK * (H / 4) + 255) / 256, 256, 0, stream>>>(oe, sel_w, slot_of, sel_e,
                                                                  b2 + (size_t)l * E * H, x);
    }
  }

  // --- final LN + tied logits (256-tile bf16 MFMA, XCD-chunked N-major) ---
  k_layernorm<4><<<NTOK / 4, 256, 0, stream>>>(x, lnfw, lnfb, nullptr, xb, nullptr, nullptr);
  bgemm<0, false, true>(stream, xb, 0, H, embB, 0, H, out, 1, 0, 0, V, nullptr, 0, NTOK, V, H,
                        1, nullptr, nullptr, nullptr);
}

// Round 12
// 1730.134 us; speedup vs baseline: 1.0224x; 1.0224x over previous
//
#include <hip/hip_runtime.h>
#include <stdint.h>

// ---------------- dims ----------------
constexpr int L = 2, Bb = 2, S = 1024, H = 768, NHd = 12, HD = 64;
constexpr int E = 8, F = 3072, V = 50257;
constexpr int NTOK = Bb * S;        // 2048
constexpr int NSLOT = NTOK * 2;     // 4096 (top-2)
constexpr float EPSLN = 1e-5f;

typedef __attribute__((ext_vector_type(4))) float f32x4;
typedef __attribute__((ext_vector_type(8))) short s16x8;

#define DEVI __device__ __forceinline__

DEVI float bf2f(short u) {
  union { float f; uint32_t i; } c; c.i = ((uint32_t)(uint16_t)u) << 16; return c.f;
}
DEVI short f2bf(float f) {
  union { float f; uint32_t i; } c; c.f = f;
  uint32_t x = c.i;
  uint32_t r = (x + 0x7fffu + ((x >> 16) & 1u)) >> 16;  // RNE
  return (short)r;
}

DEVI void gload16(const void* g, void* l) {
  __builtin_amdgcn_global_load_lds(g, l, 16, 0, 0);
}

DEVI float gelu1(float g) { return 0.5f * g * (1.f + erff(g * 0.70710678118f)); }

// ---------------- small kernels ----------------
__global__ void k_f32_to_bf16(const float* __restrict__ in, short* __restrict__ out, long n4) {
  long i = (long)blockIdx.x * blockDim.x + threadIdx.x;
  if (i >= n4) return;
  long base = i * 4;
  f32x4 v = *(const f32x4*)(in + base);
  short4 o;
  o.x = f2bf(v.x); o.y = f2bf(v.y); o.z = f2bf(v.z); o.w = f2bf(v.w);
  *(short4*)(out + base) = o;
}

// in  f32 [batch][R][C]  ->  out bf16 [batch][C][R]
__global__ void k_transpose_bf16(const float* __restrict__ in, short* __restrict__ out,
                                 int R, int C, long inBS, long outBS) {
  __shared__ float tile[32][33];
  const float* src = in + (size_t)blockIdx.z * inBS;
  short* dst = out + (size_t)blockIdx.z * outBS;
  int r0 = blockIdx.y * 32, c0 = blockIdx.x * 32;
  int tx = threadIdx.x, ty = threadIdx.y;
#pragma unroll
  for (int i = 0; i < 32; i += 8) {
    int r = r0 + ty + i, c = c0 + tx;
    if (r < R && c < C) tile[ty + i][tx] = src[(size_t)r * C + c];
  }
  __syncthreads();
#pragma unroll
  for (int i = 0; i < 32; i += 8) {
    int c = c0 + ty + i, r = r0 + tx;
    if (r < R && c < C) dst[(size_t)c * R + r] = f2bf(tile[tx][ty + i]);
  }
}

// in f32 [batch][R][C] -> hi/lo bf16 [batch][C][R]
__global__ void k_transpose_split(const float* __restrict__ in, short* __restrict__ oh,
                                  short* __restrict__ ol, int R, int C, long inBS,
                                  long outBS) {
  __shared__ float tile[32][33];
  const float* src = in + (size_t)blockIdx.z * inBS;
  short* dh = oh + (size_t)blockIdx.z * outBS;
  short* dl = ol + (size_t)blockIdx.z * outBS;
  int r0 = blockIdx.y * 32, c0 = blockIdx.x * 32;
  int tx = threadIdx.x, ty = threadIdx.y;
#pragma unroll
  for (int i = 0; i < 32; i += 8) {
    int r = r0 + ty + i, c = c0 + tx;
    if (r < R && c < C) tile[ty + i][tx] = src[(size_t)r * C + c];
  }
  __syncthreads();
#pragma unroll
  for (int i = 0; i < 32; i += 8) {
    int c = c0 + ty + i, r = r0 + tx;
    if (r < R && c < C) {
      float v = tile[tx][ty + i];
      short hi = f2bf(v);
      short lo = f2bf(v - bf2f(hi));
      dh[(size_t)c * R + r] = hi;
      dl[(size_t)c * R + r] = lo;
    }
  }
}

// in f32 [R][C] -> 3-split bf16 [C][R]   (single matrix)
__global__ void k_transpose_split3(const float* __restrict__ in, short* __restrict__ o0,
                                   short* __restrict__ o1, short* __restrict__ o2,
                                   int R, int C) {
  __shared__ float tile[32][33];
  int r0 = blockIdx.y * 32, c0 = blockIdx.x * 32;
  int tx = threadIdx.x, ty = threadIdx.y;
#pragma unroll
  for (int i = 0; i < 32; i += 8) {
    int r = r0 + ty + i, c = c0 + tx;
    if (r < R && c < C) tile[ty + i][tx] = in[(size_t)r * C + c];
  }
  __syncthreads();
#pragma unroll
  for (int i = 0; i < 32; i += 8) {
    int c = c0 + ty + i, r = r0 + tx;
    if (r < R && c < C) {
      float v = tile[tx][ty + i];
      short t0 = f2bf(v);
      float rr = v - bf2f(t0);
      short t1 = f2bf(rr);
      short t2 = f2bf(rr - bf2f(t1));
      o0[(size_t)c * R + r] = t0;
      o1[(size_t)c * R + r] = t1;
      o2[(size_t)c * R + r] = t2;
    }
  }
}

// batched QKV weight transpose+split3: z=0,1,2 selects Wq/Wk/Wv (HxH each)
__global__ void k_wqkv_t3(const float* __restrict__ Wq, const float* __restrict__ Wk,
                          const float* __restrict__ Wv, short* __restrict__ o0,
                          short* __restrict__ o1, short* __restrict__ o2) {
  __shared__ float tile[32][33];
  const int zz = blockIdx.z;
  const float* in = (zz == 0) ? Wq : (zz == 1) ? Wk : Wv;
  const size_t doff = (size_t)zz * H * H;
  int r0 = blockIdx.y * 32, c0 = blockIdx.x * 32;
  int tx = threadIdx.x, ty = threadIdx.y;
#pragma unroll
  for (int i = 0; i < 32; i += 8) {
    int r = r0 + ty + i, c = c0 + tx;
    tile[ty + i][tx] = in[(size_t)r * H + c];
  }
  __syncthreads();
#pragma unroll
  for (int i = 0; i < 32; i += 8) {
    int c = c0 + ty + i, r = r0 + tx;
    float v = tile[tx][ty + i];
    short t0 = f2bf(v);
    float rr = v - bf2f(t0);
    short t1 = f2bf(rr);
    short t2 = f2bf(rr - bf2f(t1));
    o0[doff + (size_t)c * H + r] = t0;
    o1[doff + (size_t)c * H + r] = t1;
    o2[doff + (size_t)c * H + r] = t2;
  }
}

__global__ void k_bqkv(const float* __restrict__ bq, const float* __restrict__ bk,
                       const float* __restrict__ bv, float* __restrict__ bqkv) {
  int i = blockIdx.x * blockDim.x + threadIdx.x;
  if (i >= L * 3 * H) return;
  int l = i / (3 * H), j = i % (3 * H);
  float v = (j < H) ? bq[l * H + j] : (j < 2 * H) ? bk[l * H + j - H] : bv[l * H + j - 2 * H];
  bqkv[i] = v;
}

__global__ void k_ropetab(float* __restrict__ cosT, float* __restrict__ sinT) {
  int i = blockIdx.x * blockDim.x + threadIdx.x;
  if (i >= S * (HD / 2)) return;
  int s = i / 32, d = i % 32;
  float invf = powf(10000.f, -(2.f * d) / (float)HD);
  float ang = (float)s * invf;
  cosT[i] = cosf(ang);
  sinT[i] = sinf(ang);
}

__global__ void k_embed(const int* __restrict__ ids, const float* __restrict__ emb,
                        float* __restrict__ x) {
  int idx = blockIdx.x * blockDim.x + threadIdx.x;  // NTOK*(H/4)
  int row = idx / (H / 4), c4 = idx % (H / 4);
  if (row >= NTOK) return;
  int t = ids[row];
  ((f32x4*)(x + (size_t)row * H))[c4] = ((const f32x4*)(emb + (size_t)t * H))[c4];
}

// ---------------- layernorm with fused output formats ----------------
// OUT 1: split3 -> s0,s1,s2        OUT 2: f32 of + split2 -> s0,s1
// OUT 3: f32 of + bf16 -> s0       OUT 4: bf16 -> s0
template <int OUT>
__global__ void k_layernorm(const float* __restrict__ x, const float* __restrict__ w,
                            const float* __restrict__ b, float* __restrict__ of,
                            short* __restrict__ s0, short* __restrict__ s1,
                            short* __restrict__ s2) {
  int row = blockIdx.x * (blockDim.x >> 6) + (threadIdx.x >> 6);
  int lane = threadIdx.x & 63;
  if (row >= NTOK) return;
  const float* xr = x + (size_t)row * H;
  float v[12], s = 0.f, s2s = 0.f;
#pragma unroll
  for (int j = 0; j < 12; j++) { float t = xr[lane + j * 64]; v[j] = t; s += t; s2s += t * t; }
#pragma unroll
  for (int off = 32; off; off >>= 1) { s += __shfl_xor(s, off); s2s += __shfl_xor(s2s, off); }
  float m = s / (float)H;
  float var = s2s / (float)H - m * m;
  float rs = 1.f / sqrtf(var + EPSLN);
#pragma unroll
  for (int j = 0; j < 12; j++) {
    int c = lane + j * 64;
    float val = (v[j] - m) * rs * w[c] + b[c];
    size_t idx = (size_t)row * H + c;
    if (OUT == 1) {
      short t0 = f2bf(val);
      float rr = val - bf2f(t0);
      short t1 = f2bf(rr);
      short t2 = f2bf(rr - bf2f(t1));
      s0[idx] = t0; s1[idx] = t1; s2[idx] = t2;
    } else if (OUT == 2) {
      of[idx] = val;
      short hi = f2bf(val);
      s0[idx] = hi; s1[idx] = f2bf(val - bf2f(hi));
    } else if (OUT == 3) {
      of[idx] = val;
      s0[idx] = f2bf(val);
    } else {
      s0[idx] = f2bf(val);
    }
  }
}

// ---------------- softmax over hi/lo bf16 scores, in place -------------------
__global__ void k_softmax2(short* __restrict__ p0, short* __restrict__ p1) {
  int row = blockIdx.x * 4 + (threadIdx.x >> 6);  // B*NH*S rows
  int lane = threadIdx.x & 63;
  s16x8* r0 = (s16x8*)(p0 + (size_t)row * S + lane * 16);
  s16x8* r1 = (s16x8*)(p1 + (size_t)row * S + lane * 16);
  s16x8 h0 = r0[0], h1 = r0[1];
  s16x8 l0 = r1[0], l1 = r1[1];
  float v[16];
#pragma unroll
  for (int j = 0; j < 8; j++) {
    v[j] = bf2f(h0[j]) + bf2f(l0[j]);
    v[8 + j] = bf2f(h1[j]) + bf2f(l1[j]);
  }
  float mx = -3e38f;
#pragma unroll
  for (int j = 0; j < 16; j++) mx = fmaxf(mx, v[j]);
#pragma unroll
  for (int off = 32; off; off >>= 1) mx = fmaxf(mx, __shfl_xor(mx, off));
  float sum = 0.f;
#pragma unroll
  for (int j = 0; j < 16; j++) { v[j] = expf(v[j] - mx); sum += v[j]; }
#pragma unroll
  for (int off = 32; off; off >>= 1) sum += __shfl_xor(sum, off);
  float inv = 1.f / sum;
#pragma unroll
  for (int j = 0; j < 16; j++) v[j] *= inv;
  s16x8 oh0, oh1, ol0, ol1;
#pragma unroll
  for (int j = 0; j < 8; j++) {
    short hi = f2bf(v[j]);
    oh0[j] = hi; ol0[j] = f2bf(v[j] - bf2f(hi));
    short hi2 = f2bf(v[8 + j]);
    oh1[j] = hi2; ol1[j] = f2bf(v[8 + j] - bf2f(hi2));
  }
  r0[0] = oh0; r0[1] = oh1;
  r1[0] = ol0; r1[1] = ol1;
}

// ---------------- router (f32 h input -> exact top-2) ----------------
__global__ void k_router(const float* __restrict__ h, const float* __restrict__ Wr,
                         const float* __restrict__ br, float* __restrict__ sel_w,
                         int* __restrict__ sel_e, int* __restrict__ counts) {
  int tok = blockIdx.x * (blockDim.x >> 6) + (threadIdx.x >> 6);
  int lane = threadIdx.x & 63;
  if (tok >= NTOK) return;
  const float* hr = h + (size_t)tok * H;
  float acc[8] = {0, 0, 0, 0, 0, 0, 0, 0};
  for (int i = lane; i < H; i += 64) {
    float hv = hr[i];
    const f32x4* w4 = (const f32x4*)(Wr + (size_t)i * E);
    f32x4 a = w4[0], b = w4[1];
    acc[0] += hv * a.x; acc[1] += hv * a.y; acc[2] += hv * a.z; acc[3] += hv * a.w;
    acc[4] += hv * b.x; acc[5] += hv * b.y; acc[6] += hv * b.z; acc[7] += hv * b.w;
  }
#pragma unroll
  for (int off = 32; off; off >>= 1)
#pragma unroll
    for (int e = 0; e < 8; e++) acc[e] += __shfl_xor(acc[e], off);
  if (lane == 0) {
    float lg[8], m = -3e38f;
#pragma unroll
    for (int e = 0; e < 8; e++) { lg[e] = acc[e] + br[e]; m = fmaxf(m, lg[e]); }
    float sum = 0.f;
#pragma unroll
    for (int e = 0; e < 8; e++) { lg[e] = expf(lg[e] - m); sum += lg[e]; }
    float inv = 1.f / sum;
#pragma unroll
    for (int e = 0; e < 8; e++) lg[e] *= inv;
    int i1 = 0;
#pragma unroll
    for (int e = 1; e < 8; e++) if (lg[e] > lg[i1]) i1 = e;
    int i2 = (i1 == 0) ? 1 : 0;
#pragma unroll
    for (int e = 0; e < 8; e++) if (e != i1 && lg[e] > lg[i2]) i2 = e;
    float p1 = lg[i1], p2 = lg[i2];
    float ws = p1 + p2 + 1e-9f;
    sel_e[tok * 2] = i1; sel_e[tok * 2 + 1] = i2;
    sel_w[tok * 2] = p1 / ws; sel_w[tok * 2 + 1] = p2 / ws;
    atomicAdd(counts + i1, 1);
    atomicAdd(counts + i2, 1);
  }
}

__global__ void k_offsets(const int* __restrict__ counts, int* __restrict__ offs) {
  if (threadIdx.x == 0) {
    int a = 0;
    for (int e = 0; e < E; e++) { offs[e] = a; a += counts[e]; }
    offs[E] = a;
  }
}

__global__ void k_scatter(const int* __restrict__ sel_e, const int* __restrict__ offs,
                          int* __restrict__ cursor, int* __restrict__ tok_list,
                          int* __restrict__ slot_of) {
  int tok = blockIdx.x * blockDim.x + threadIdx.x;
  if (tok >= NTOK) return;
  for (int k = 0; k < 2; k++) {
    int e = sel_e[tok * 2 + k];
    int pos = atomicAdd(cursor + e, 1);
    int g = offs[e] + pos;
    tok_list[g] = tok;
    slot_of[tok * 2 + k] = g;
  }
}

// ff = sum_k w_k * (oe[slot_k] + b2[e_k]); x += ff
__global__ void k_combine(const float* __restrict__ oe, const float* __restrict__ sel_w,
                          const int* __restrict__ slot_of, const int* __restrict__ sel_e,
                          const float* __restrict__ b2, float* __restrict__ x) {
  int idx = blockIdx.x * blockDim.x + threadIdx.x;  // NTOK*(H/4)
  if (idx >= NTOK * (H / 4)) return;
  int tok = idx / (H / 4), c4 = idx % (H / 4);
  float w0 = sel_w[tok * 2], w1 = sel_w[tok * 2 + 1];
  int s0 = slot_of[tok * 2], s1 = slot_of[tok * 2 + 1];
  int e0 = sel_e[tok * 2], e1 = sel_e[tok * 2 + 1];
  f32x4 a = ((const f32x4*)(oe + (size_t)s0 * H))[c4];
  f32x4 b = ((const f32x4*)(oe + (size_t)s1 * H))[c4];
  f32x4 ba = ((const f32x4*)(b2 + (size_t)e0 * H))[c4];
  f32x4 bb = ((const f32x4*)(b2 + (size_t)e1 * H))[c4];
  f32x4* xp = (f32x4*)(x + (size_t)tok * H) + c4;
  *xp = *xp + w0 * (a + ba) + w1 * (b + bb);
}

// ---------------- split-MFMA GEMM: C = (ΣA_s)·(ΣB_s)^T, products i+j<SP -----
// SP=2: 3 MFMAs/frag; SP=3: 6 MFMAs/frag.
// MODE 0: f32 out (+bias opt)   1: f32 out = res + acc + bias
// MODE 6: gelu(acc+bias) -> split2 bf16 (Cp,Cp2)
// MODE 7: acc*alpha + causal -> split2 bf16 (Cp,Cp2)
// MODE 8: acc -> split3 bf16 (Cp,Cp2,Cp3)
// MODE 9: QKV fused: bias + RoPE + split3(q->Cp..3, k->K0..2) / split2(v->V0,V1)
template <int SP, int MODE, bool GATHER>
__global__ __launch_bounds__(256, 2) void k_bgemmS(
    const short* __restrict__ A0, const short* __restrict__ A1, const short* __restrict__ A2,
    long sAz, int lda,
    const short* __restrict__ B0, const short* __restrict__ B1, const short* __restrict__ B2,
    long sBz, int ldb,
    void* __restrict__ Cp, void* __restrict__ Cp2, void* __restrict__ Cp3,
    short* __restrict__ K0, short* __restrict__ K1, short* __restrict__ K2,
    short* __restrict__ V0, short* __restrict__ V1,
    const float* __restrict__ cT, const float* __restrict__ sT,
    int zdiv, long sChi, long sClo, int ldc,
    const float* __restrict__ res, const float* __restrict__ bias, long sBias,
    int M, int N, int K,
    const int* __restrict__ d_counts, const int* __restrict__ d_offs,
    const int* __restrict__ gidx, float alpha) {
  const int z = blockIdx.z;
  const int Meff = d_counts ? d_counts[z] : M;
  const int tm = blockIdx.y;
  if (tm * 128 >= Meff) return;
  const int tn = blockIdx.x;
  const int row_base = d_offs ? d_offs[z] : 0;

  __shared__ short Ab[SP][128 * 32];
  __shared__ short Bb2[SP][128 * 32];

  const int tid = threadIdx.x;
  const int lane = tid & 63;
  const int w = tid >> 6;

  const short* APz[3];
  const short* BPz[3];
  APz[0] = A0 + (size_t)z * sAz;
  APz[1] = A1 + (size_t)z * sAz;
  APz[2] = (SP > 2) ? (A2 + (size_t)z * sAz) : APz[0];
  BPz[0] = B0 + (size_t)z * sBz;
  BPz[1] = B1 + (size_t)z * sBz;
  BPz[2] = (SP > 2) ? (B2 + (size_t)z * sBz) : BPz[0];

  size_t aOff[2], bOff[2];
#pragma unroll
  for (int i = 0; i < 2; ++i) {
    const int srow = i * 64 + (tid >> 2);
    const int kb = (tid & 3) ^ (srow & 3);  // pre-swizzled source (involution)
    int lrow = tm * 128 + srow;
    if (lrow > Meff - 1) lrow = Meff - 1;
    int ar = row_base + lrow;
    if (GATHER) ar = gidx[ar];
    aOff[i] = (size_t)ar * lda + kb * 8;
    int bcol = tn * 128 + srow;
    if (bcol > N - 1) bcol = N - 1;
    bOff[i] = (size_t)bcol * ldb + kb * 8;
  }

  f32x4 acc[4][4];
#pragma unroll
  for (int a = 0; a < 4; ++a)
#pragma unroll
    for (int b = 0; b < 4; ++b) acc[a][b] = {0.f, 0.f, 0.f, 0.f};

  const int wr = (w >> 1) * 64;
  const int wc = (w & 1) * 64;
  const int r16 = lane & 15;
  const int kb4 = lane >> 4;
  const int swz = (kb4 ^ (r16 & 3)) * 8;
  int aoff[4], boff[4];
#pragma unroll
  for (int i = 0; i < 4; ++i) {
    aoff[i] = (wr + i * 16 + r16) * 32 + swz;
    boff[i] = (wc + i * 16 + r16) * 32 + swz;
  }

  for (int k0 = 0; k0 < K; k0 += 32) {
#pragma unroll
    for (int s = 0; s < SP; ++s) {
      gload16(APz[s] + aOff[0], (char*)(&Ab[s][0]) + w * 1024);
      gload16(APz[s] + aOff[1], (char*)(&Ab[s][0]) + 4096 + w * 1024);
      gload16(BPz[s] + bOff[0], (char*)(&Bb2[s][0]) + w * 1024);
      gload16(BPz[s] + bOff[1], (char*)(&Bb2[s][0]) + 4096 + w * 1024);
    }
    aOff[0] += 32; aOff[1] += 32; bOff[0] += 32; bOff[1] += 32;
    __syncthreads();
    s16x8 af[SP][4], bf[SP][4];
#pragma unroll
    for (int s = 0; s < SP; ++s)
#pragma unroll
      for (int i = 0; i < 4; ++i) {
        af[s][i] = *(const s16x8*)(&Ab[s][aoff[i]]);
        bf[s][i] = *(const s16x8*)(&Bb2[s][boff[i]]);
      }
#pragma unroll
    for (int mi = 0; mi < 4; ++mi)
#pragma unroll
      for (int ni = 0; ni < 4; ++ni) {
        f32x4 a = acc[mi][ni];
#pragma unroll
        for (int si = 0; si < SP; ++si)
#pragma unroll
          for (int sj = 0; sj < SP - si; ++sj)
            a = __builtin_amdgcn_mfma_f32_16x16x32_bf16(af[si][mi], bf[sj][ni], a, 0, 0, 0);
        acc[mi][ni] = a;
      }
    __syncthreads();
  }

  const float* bz = bias ? (bias + (size_t)z * sBias) : nullptr;
  const int q4 = lane >> 4;
  float bvv[4];
  int gco[4];
#pragma unroll
  for (int ni = 0; ni < 4; ++ni) {
    gco[ni] = tn * 128 + wc + ni * 16 + r16;
    bvv[ni] = (bz && gco[ni] < N) ? bz[gco[ni]] : 0.f;
  }

  if (MODE == 9) {
    // QKV fused epilogue: cols = [q(768) | k(768) | v(768)], heads of 64.
    const int sec_base = tn * 128 + wc;     // multiple of 64, aligned to sections
    const int sec = sec_base / H;           // 0=q, 1=k, 2=v
    const int hh = (sec_base % H) / HD;
#pragma unroll
    for (int mi = 0; mi < 4; ++mi) {
#pragma unroll
      for (int j = 0; j < 4; ++j) {
        const int row = tm * 128 + wr + mi * 16 + q4 * 4 + j;   // token
        const int ss = row & (S - 1);
        const long zz = (long)((row >> 10) * NHd + hh);
#pragma unroll
        for (int ni = 0; ni < 2; ++ni) {
          const int d = ni * 16 + r16;                          // 0..31
          float a1 = acc[mi][ni][j] + bvv[ni];
          float a2 = acc[mi][ni + 2][j] + bvv[ni + 2];
          if (sec < 2) {
            float cc = cT[ss * 32 + d], sn = sT[ss * 32 + d];
            float r1 = a1 * cc - a2 * sn;
            float r2 = a2 * cc + a1 * sn;
            const long bi = (zz * S + ss) * HD + d;
            short* d0 = (sec == 0) ? (short*)Cp : K0;
            short* d1 = (sec == 0) ? (short*)Cp2 : K1;
            short* d2 = (sec == 0) ? (short*)Cp3 : K2;
            short t0 = f2bf(r1); float rr = r1 - bf2f(t0);
            short t1 = f2bf(rr); short t2 = f2bf(rr - bf2f(t1));
            d0[bi] = t0; d1[bi] = t1; d2[bi] = t2;
            t0 = f2bf(r2); rr = r2 - bf2f(t0);
            t1 = f2bf(rr); t2 = f2bf(rr - bf2f(t1));
            d0[bi + 32] = t0; d1[bi + 32] = t1; d2[bi + 32] = t2;
          } else {
            const long vb1 = zz * HD * S + (long)d * S + ss;
            short hv = f2bf(a1);
            V0[vb1] = hv; V1[vb1] = f2bf(a1 - bf2f(hv));
            const long vb2 = vb1 + 32L * S;
            hv = f2bf(a2);
            V0[vb2] = hv; V1[vb2] = f2bf(a2 - bf2f(hv));
          }
        }
      }
    }
    return;
  }

  const long out_off = (long)(z / zdiv) * sChi + (long)(z % zdiv) * sClo;
#pragma unroll
  for (int mi = 0; mi < 4; ++mi) {
#pragma unroll
    for (int j = 0; j < 4; ++j) {
      const int lrow = tm * 128 + wr + mi * 16 + q4 * 4 + j;
      if (lrow >= Meff) continue;
      const long rbase = out_off + (long)(row_base + lrow) * ldc;
#pragma unroll
      for (int ni = 0; ni < 4; ++ni) {
        if (gco[ni] >= N) continue;
        const float v = acc[mi][ni][j];
        const long idx = rbase + gco[ni];
        if (MODE == 0) {
          ((float*)Cp)[idx] = v + bvv[ni];
        } else if (MODE == 1) {
          ((float*)Cp)[idx] = res[idx] + v + bvv[ni];
        } else if (MODE == 6) {
          float g = gelu1(v + bvv[ni]);
          short hi = f2bf(g);
          ((short*)Cp)[idx] = hi;
          ((short*)Cp2)[idx] = f2bf(g - bf2f(hi));
        } else if (MODE == 7) {
          float g = v * alpha + ((gco[ni] > lrow) ? -1e9f : 0.f);
          short hi = f2bf(g);
          ((short*)Cp)[idx] = hi;
          ((short*)Cp2)[idx] = f2bf(g - bf2f(hi));
        } else if (MODE == 8) {
          float g = v + bvv[ni];
          short t0 = f2bf(g); float rr = g - bf2f(t0);
          short t1 = f2bf(rr); short t2 = f2bf(rr - bf2f(t1));
          ((short*)Cp)[idx] = t0;
          ((short*)Cp2)[idx] = t1;
          ((short*)Cp3)[idx] = t2;
        }
      }
    }
  }
}

template <int SP, int MODE, bool GATHER>
static void bgemmS(hipStream_t st, const short* A0, const short* A1, const short* A2, long sAz,
                   int lda, const short* B0, const short* B1, const short* B2, long sBz,
                   int ldb, void* C, void* C2, void* C3, int zdiv, long sChi, long sClo,
                   int ldc, const float* res, const float* bias, long sBias, int M, int N,
                   int K, int nz, const int* cnts, const int* offs_, const int* gat,
                   float alpha, short* K0 = nullptr, short* K1 = nullptr, short* K2 = nullptr,
                   short* V0 = nullptr, short* V1 = nullptr, const float* cT = nullptr,
                   const float* sT = nullptr) {
  dim3 g((N + 127) / 128, (M + 127) / 128, nz);
  k_bgemmS<SP, MODE, GATHER><<<g, 256, 0, st>>>(A0, A1, A2, sAz, lda, B0, B1, B2, sBz, ldb, C,
                                                C2, C3, K0, K1, K2, V0, V1, cT, sT, zdiv, sChi,
                                                sClo, ldc, res, bias, sBias, M, N, K, cnts,
                                                offs_, gat, alpha);
}

// ------- plain bf16 MFMA GEMM, 128x128 tile, BK=64, double-buffered LDS -----
// T3 "minimum 2-phase": stage tile t+1 into the OTHER (named) buffer, compute
// tile t, then ONE __syncthreads (its vmcnt drain overlaps the MFMA phase).
// Same ascending-K accumulation order as before (bit-identical results).
// MODE 0: f32 out (+bias opt)   4: bf16 out = gelu(acc + bias)
// NSWZ: N-major + bijective XCD-chunk swizzle (B-tile L2 locality).
template <int MODE, bool GATHER, bool NSWZ>
__global__ __launch_bounds__(256, 2) void k_bgemm(
    const short* __restrict__ A, long sAz, int lda,
    const short* __restrict__ Bt, long sBz, int ldb,
    void* __restrict__ Cp, int zdiv, long sChi, long sClo, int ldc,
    const float* __restrict__ bias, long sBias,
    int M, int N, int K,
    const int* __restrict__ d_counts, const int* __restrict__ d_offs,
    const int* __restrict__ gidx) {
  const int z = blockIdx.z;
  const int Meff = d_counts ? d_counts[z] : M;
  int tm, tn;
  if (NSWZ) {
    const int bid = blockIdx.y * gridDim.x + blockIdx.x;
    const int nwg = gridDim.x * gridDim.y;
    const int q = nwg >> 3, r = nwg & 7;
    const int xcd = bid & 7, ix = bid >> 3;
    const int wg = (xcd < r) ? (xcd * (q + 1) + ix) : (r * (q + 1) + (xcd - r) * q + ix);
    tn = wg / gridDim.y;   // N-major: consecutive wg share tn
    tm = wg % gridDim.y;
  } else {
    tm = blockIdx.y;
    tn = blockIdx.x;
  }
  if (tm * 128 >= Meff) return;
  const int row_base = d_offs ? d_offs[z] : 0;

  __shared__ short Ab0[128 * 64];   // 16 KB each; named -> static alias sep.
  __shared__ short Ab1[128 * 64];
  __shared__ short Bb0[128 * 64];
  __shared__ short Bb1[128 * 64];

  const int tid = threadIdx.x;
  const int lane = tid & 63;
  const int w = tid >> 6;

  const short* Az = A + (size_t)z * sAz;
  const short* Bz = Bt + (size_t)z * sBz;

  // staging: chunk c = w*4+i covers LDS rows c*8..c*8+7; lane -> row c*8+(lane>>3),
  // k-unit lane&7; source k pre-swizzled by (row&7)^unit (involution, rule #21).
  const int swzS = ((lane >> 3) ^ (lane & 7)) * 8;
  const short* aSrc[4];
  const short* bSrc[4];
#pragma unroll
  for (int i = 0; i < 4; ++i) {
    const int rin = (w * 4 + i) * 8 + (lane >> 3);  // 0..127
    int lrow = tm * 128 + rin;
    if (lrow > Meff - 1) lrow = Meff - 1;
    int ar = row_base + lrow;
    if (GATHER) ar = gidx[ar];
    aSrc[i] = Az + (size_t)ar * lda + swzS;
    int bcol = tn * 128 + rin;
    if (bcol > N - 1) bcol = N - 1;
    bSrc[i] = Bz + (size_t)bcol * ldb + swzS;
  }

  f32x4 acc[4][4];
#pragma unroll
  for (int a = 0; a < 4; ++a)
#pragma unroll
    for (int b = 0; b < 4; ++b) acc[a][b] = {0.f, 0.f, 0.f, 0.f};

  const int wr = (w >> 1) * 64;
  const int wc = (w & 1) * 64;
  const int r16 = lane & 15;
  const int kb4 = lane >> 4;
  int aoff[4][2], boff[4][2];
#pragma unroll
  for (int i = 0; i < 4; ++i) {
#pragma unroll
    for (int kw = 0; kw < 2; ++kw) {
      const int sw = ((r16 & 7) ^ (kw * 4 + kb4)) * 8;
      aoff[i][kw] = (wr + i * 16 + r16) * 64 + sw;
      boff[i][kw] = (wc + i * 16 + r16) * 64 + sw;
    }
  }

  auto stage = [&](short* Ad, short* Bd) {
#pragma unroll
    for (int i = 0; i < 4; ++i) gload16(aSrc[i], (char*)Ad + (w * 4 + i) * 1024);
#pragma unroll
    for (int i = 0; i < 4; ++i) gload16(bSrc[i], (char*)Bd + (w * 4 + i) * 1024);
#pragma unroll
    for (int i = 0; i < 4; ++i) { aSrc[i] += 64; bSrc[i] += 64; }
  };
  auto compute = [&](const short* Ad, const short* Bd) {
#pragma unroll
    for (int kw = 0; kw < 2; ++kw) {
      s16x8 af[4], bf[4];
#pragma unroll
      for (int i = 0; i < 4; ++i) {
        af[i] = *(const s16x8*)(Ad + aoff[i][kw]);
        bf[i] = *(const s16x8*)(Bd + boff[i][kw]);
      }
#pragma unroll
      for (int mi = 0; mi < 4; ++mi)
#pragma unroll
        for (int ni = 0; ni < 4; ++ni)
          acc[mi][ni] =
              __builtin_amdgcn_mfma_f32_16x16x32_bf16(af[mi], bf[ni], acc[mi][ni], 0, 0, 0);
    }
  };

  // prologue: stage tile 0 into buffer 0
  stage(Ab0, Bb0);
  __syncthreads();
  const int nt = K / 64;
  for (int t = 0; t < nt; t += 2) {
    if (t + 1 < nt) stage(Ab1, Bb1);     // loads fly under the MFMA phase below
    compute(Ab0, Bb0);
    __syncthreads();                     // vmcnt drain AFTER compute (overlapped)
    if (t + 1 < nt) {
      if (t + 2 < nt) stage(Ab0, Bb0);
      compute(Ab1, Bb1);
      __syncthreads();
    }
  }

  const long out_off = (long)(z / zdiv) * sChi + (long)(z % zdiv) * sClo;
  const float* bz = bias ? (bias + (size_t)z * sBias) : nullptr;
  const int q4 = lane >> 4;
  float bvv[4];
  int gco[4];
#pragma unroll
  for (int ni = 0; ni < 4; ++ni) {
    gco[ni] = tn * 128 + wc + ni * 16 + r16;
    bvv[ni] = (bz && gco[ni] < N) ? bz[gco[ni]] : 0.f;
  }
#pragma unroll
  for (int mi = 0; mi < 4; ++mi) {
#pragma unroll
    for (int j = 0; j < 4; ++j) {
      const int lrow = tm * 128 + wr + mi * 16 + q4 * 4 + j;
      if (lrow >= Meff) continue;
      const long rbase = out_off + (row_base + lrow) * (long)ldc;
#pragma unroll
      for (int ni = 0; ni < 4; ++ni) {
        if (gco[ni] >= N) continue;
        const float v = acc[mi][ni][j];
        if (MODE == 0) {
          ((float*)Cp)[rbase + gco[ni]] = v + bvv[ni];
        } else if (MODE == 4) {
          float g = v + bvv[ni];
          ((short*)Cp)[rbase + gco[ni]] = f2bf(gelu1(g));
        }
      }
    }
  }
}

template <int MODE, bool GATHER, bool NSWZ>
static void bgemm(hipStream_t st, const short* A, long sAz, int lda, const short* Bt, long sBz,
                  int ldb, void* C, int zdiv, long sChi, long sClo, int ldc, const float* bias,
                  long sBias, int M, int N, int K, int nz, const int* cnts, const int* offs_,
                  const int* gat) {
  dim3 g((N + 127) / 128, (M + 127) / 128, nz);
  k_bgemm<MODE, GATHER, NSWZ><<<g, 256, 0, st>>>(A, sAz, lda, Bt, sBz, ldb, C, zdiv, sChi,
                                                 sClo, ldc, bias, sBias, M, N, K, cnts, offs_,
                                                 gat);
}

// ---------------- launch ----------------
extern "C" void kernel_launch(void* const* d_in, const int* in_sizes, int n_in, void* d_out,
                              int out_size, void* d_ws, size_t ws_size, hipStream_t stream) {
  (void)in_sizes; (void)n_in; (void)out_size; (void)ws_size;
  const int*   ids  = (const int*)d_in[0];
  const float* emb  = (const float*)d_in[1];
  const float* ln1w = (const float*)d_in[2];
  const float* ln1b = (const float*)d_in[3];
  const float* ln2w = (const float*)d_in[4];
  const float* ln2b = (const float*)d_in[5];
  const float* lnfw = (const float*)d_in[6];
  const float* lnfb = (const float*)d_in[7];
  const float* Wq = (const float*)d_in[8];
  const float* bq = (const float*)d_in[9];
  const float* Wk = (const float*)d_in[10];
  const float* bk = (const float*)d_in[11];
  const float* Wv = (const float*)d_in[12];
  const float* bv = (const float*)d_in[13];
  const float* Wo = (const float*)d_in[14];
  const float* bo = (const float*)d_in[15];
  const float* Wr = (const float*)d_in[16];
  const float* br = (const float*)d_in[17];
  const float* W1 = (const float*)d_in[18];
  const float* b1 = (const float*)d_in[19];
  const float* W2 = (const float*)d_in[20];
  const float* b2 = (const float*)d_in[21];
  float* out = (float*)d_out;

  char* p = (char*)d_ws;
  auto alloc = [&](size_t bytes) {
    char* r = p;
    p += (bytes + 255) & ~(size_t)255;
    return r;
  };
  short* embB = (short*)alloc((size_t)V * H * 2);               // 77.2 MB
  // big region (100.7 MB), time-shared: attention [p0|p1] vs MoE [R_hi|R_lo]
  char* big = alloc((size_t)Bb * NHd * S * S * 2 * 2);
  short* p0   = (short*)big;
  short* p1   = p0 + (size_t)Bb * NHd * S * S;
  short* R_hi = (short*)big;
  short* R_lo = R_hi + (size_t)E * F * H;
  short* Wb0 = (short*)alloc((size_t)3 * H * H * 2);            // QKV W^T 3-splits
  short* Wb1 = (short*)alloc((size_t)3 * H * H * 2);
  short* Wb2 = (short*)alloc((size_t)3 * H * H * 2);
  short* Wo0 = (short*)alloc((size_t)H * H * 2);                // Wo^T 3-splits
  short* Wo1 = (short*)alloc((size_t)H * H * 2);
  short* Wo2 = (short*)alloc((size_t)H * H * 2);
  float* bqkv = (float*)alloc((size_t)L * 3 * H * 4);
  float* cosT = (float*)alloc((size_t)S * 32 * 4);
  float* sinT = (float*)alloc((size_t)S * 32 * 4);
  float* x    = (float*)alloc((size_t)NTOK * H * 4);
  float* hbuf = (float*)alloc((size_t)NTOK * H * 4);
  short* xb   = (short*)alloc((size_t)NTOK * H * 2);
  short* xb2  = (short*)alloc((size_t)NTOK * H * 2);
  short* h_hi = (short*)alloc((size_t)NTOK * H * 2);
  short* h_lo = (short*)alloc((size_t)NTOK * H * 2);
  short* h30  = (short*)alloc((size_t)NTOK * H * 2);
  short* h31  = (short*)alloc((size_t)NTOK * H * 2);
  short* h32  = (short*)alloc((size_t)NTOK * H * 2);
  short* q30  = (short*)alloc((size_t)NTOK * H * 2);
  short* q31  = (short*)alloc((size_t)NTOK * H * 2);
  short* q32  = (short*)alloc((size_t)NTOK * H * 2);
  short* k30  = (short*)alloc((size_t)NTOK * H * 2);
  short* k31  = (short*)alloc((size_t)NTOK * H * 2);
  short* k32  = (short*)alloc((size_t)NTOK * H * 2);
  short* v20  = (short*)alloc((size_t)NTOK * H * 2);
  short* v21  = (short*)alloc((size_t)NTOK * H * 2);
  short* o30  = (short*)alloc((size_t)NTOK * H * 2);
  short* o31  = (short*)alloc((size_t)NTOK * H * 2);
  short* o32  = (short*)alloc((size_t)NTOK * H * 2);
  // union region (63.1 MB): act_hi+act_lo (l0) / act_b (l1) + oe
  char* uni = alloc((size_t)NSLOT * F * 4 + (size_t)NSLOT * H * 4);
  short* act_hi = (short*)uni;
  short* act_lo = (short*)(uni + (size_t)NSLOT * F * 2);
  short* act_b  = (short*)uni;
  float* oe     = (float*)(uni + (size_t)NSLOT * F * 4);
  int* counts  = (int*)alloc(2 * E * 4);
  int* cursor  = counts + E;
  int* offs    = (int*)alloc((E + 1) * 4);
  int* sel_e   = (int*)alloc((size_t)NTOK * 2 * 4);
  float* sel_w = (float*)alloc((size_t)NTOK * 2 * 4);
  int* slot_of = (int*)alloc((size_t)NTOK * 2 * 4);
  int* tok_lst = (int*)alloc((size_t)NSLOT * 4);

  // ---- prologue ----
  long nEmb4 = (long)V * H / 4;
  k_f32_to_bf16<<<(nEmb4 + 255) / 256, 256, 0, stream>>>(emb, embB, nEmb4);
  k_bqkv<<<(L * 3 * H + 255) / 256, 256, 0, stream>>>(bq, bk, bv, bqkv);
  k_ropetab<<<(S * 32 + 255) / 256, 256, 0, stream>>>(cosT, sinT);
  k_embed<<<(NTOK * (H / 4) + 255) / 256, 256, 0, stream>>>(ids, emb, x);

  dim3 tb(32, 8);
  const dim3 tHH(H / 32, H / 32, 1);

  for (int l = 0; l < L; l++) {
    // --- attention (bf16x6 split-MFMA; upstream of routers) ---
    k_layernorm<1><<<NTOK / 4, 256, 0, stream>>>(x, ln1w + l * H, ln1b + l * H, nullptr, h30,
                                                 h31, h32);
    k_wqkv_t3<<<dim3(H / 32, H / 32, 3), tb, 0, stream>>>(
        Wq + (size_t)l * H * H, Wk + (size_t)l * H * H, Wv + (size_t)l * H * H, Wb0, Wb1, Wb2);
    // QKV fused with bias+RoPE+splits (MODE 9)
    bgemmS<3, 9, false>(stream, h30, h31, h32, 0, H, Wb0, Wb1, Wb2, 0, H, q30, q31, q32, 1, 0,
                        0, 0, nullptr, bqkv + l * 3 * H, 0, NTOK, 3 * H, H, 1, nullptr,
                        nullptr, nullptr, 1.f, k30, k31, k32, v20, v21, cosT, sinT);
    // QK^T: scale+causal -> hi/lo bf16 scores
    bgemmS<3, 7, false>(stream, q30, q31, q32, (long)S * HD, HD, k30, k31, k32, (long)S * HD,
                        HD, p0, p1, nullptr, 1, (long)S * S, 0, S, nullptr, nullptr, 0, S, S,
                        HD, Bb * NHd, nullptr, nullptr, nullptr, 0.125f);
    k_softmax2<<<(Bb * NHd * S) / 4, 256, 0, stream>>>(p0, p1);
    // PV -> o split3 (MODE 8)
    bgemmS<2, 8, false>(stream, p0, p1, nullptr, (long)S * S, S, v20, v21, nullptr,
                        (long)HD * S, S, o30, o31, o32, NHd, (long)S * H, HD, H, nullptr,
                        nullptr, 0, S, HD, S, Bb * NHd, nullptr, nullptr, nullptr, 1.f);
    // Wo: x += o @ Wo + bo
    k_transpose_split3<<<tHH, tb, 0, stream>>>(Wo + (size_t)l * H * H, Wo0, Wo1, Wo2, H, H);
    bgemmS<3, 1, false>(stream, o30, o31, o32, 0, H, Wo0, Wo1, Wo2, 0, H, x, nullptr, nullptr,
                        1, 0, 0, H, x, bo + l * H, 0, NTOK, H, H, 1, nullptr, nullptr, nullptr,
                        1.f);

    // --- MoE ---
    if (l == 0)
      k_layernorm<2><<<NTOK / 4, 256, 0, stream>>>(x, ln2w + l * H, ln2b + l * H, hbuf, h_hi,
                                                   h_lo, nullptr);
    else
      k_layernorm<3><<<NTOK / 4, 256, 0, stream>>>(x, ln2w + l * H, ln2b + l * H, hbuf, xb2,
                                                   nullptr, nullptr);
    hipMemsetAsync(counts, 0, 2 * E * sizeof(int), stream);
    k_router<<<NTOK / 4, 256, 0, stream>>>(hbuf, Wr + (size_t)l * H * E, br + l * E, sel_w,
                                           sel_e, counts);
    k_offsets<<<1, 64, 0, stream>>>(counts, offs);
    k_scatter<<<(NTOK + 255) / 256, 256, 0, stream>>>(sel_e, offs, cursor, tok_lst, slot_of);
    if (l == 0) {
      // bf16x3 split MFMA experts (proven path; p0/p1 dead -> R region free)
      k_transpose_split<<<dim3(F / 32, H / 32, E), tb, 0, stream>>>(
          W1, R_hi, R_lo, H, F, (long)H * F, (long)F * H);
      bgemmS<2, 6, true>(stream, h_hi, h_lo, nullptr, 0, H, R_hi, R_lo, nullptr, (long)F * H,
                         H, act_hi, act_lo, nullptr, 1, 0, 0, F, nullptr, b1, F, NSLOT, F, H,
                         E, counts, offs, tok_lst, 1.f);
      k_transpose_split<<<dim3(H / 32, F / 32, E), tb, 0, stream>>>(
          W2, R_hi, R_lo, F, H, (long)F * H, (long)H * F);
      bgemmS<2, 0, false>(stream, act_hi, act_lo, nullptr, 0, F, R_hi, R_lo, nullptr,
                          (long)H * F, F, oe, nullptr, nullptr, 1, 0, 0, H, nullptr, nullptr,
                          0, NSLOT, H, F, E, counts, offs, nullptr, 1.f);
      k_combine<<<(NTOK * (H / 4) + 255) / 256, 256, 0, stream>>>(oe, sel_w, slot_of, sel_e,
                                                                  b2, x);
    } else {
      // plain bf16 MFMA experts (128-tile BK=64, dbuf); stage l1 weights
      k_transpose_bf16<<<dim3(F / 32, H / 32, E), tb, 0, stream>>>(
          W1 + (size_t)1 * E * H * F, R_hi, H, F, (long)H * F, (long)F * H);
      k_transpose_bf16<<<dim3(H / 32, F / 32, E), tb, 0, stream>>>(
          W2 + (size_t)1 * E * F * H, R_lo, F, H, (long)F * H, (long)H * F);
      bgemm<4, true, false>(stream, xb2, 0, H, R_hi, (long)F * H, H, act_b, 1, 0, 0, F,
                            b1 + (size_t)l * E * F, F, NSLOT, F, H, E, counts, offs, tok_lst);
      bgemm<0, false, false>(stream, act_b, 0, F, R_lo, (long)H * F, F, oe, 1, 0, 0, H,
                             nullptr, 0, NSLOT, H, F, E, counts, offs, nullptr);
      k_combine<<<(NTOK * (H / 4) + 255) / 256, 256, 0, stream>>>(oe, sel_w, slot_of, sel_e,
                                                                  b2 + (size_t)l * E * H, x);
    }
  }

  // --- final LN + tied logits (128-tile dbuf bf16 MFMA, XCD-chunked N-major) ---
  k_layernorm<4><<<NTOK / 4, 256, 0, stream>>>(x, lnfw, lnfb, nullptr, xb, nullptr, nullptr);
  bgemm<0, false, true>(stream, xb, 0, H, embB, 0, H, out, 1, 0, 0, V, nullptr, 0, NTOK, V, H,
                        1, nullptr, nullptr, nullptr);
}

// Round 13
// 1685.552 us; speedup vs baseline: 1.0495x; 1.0264x over previous
//
#include <hip/hip_runtime.h>
#include <stdint.h>

// ---------------- dims ----------------
constexpr int L = 2, Bb = 2, S = 1024, H = 768, NHd = 12, HD = 64;
constexpr int E = 8, F = 3072, V = 50257;
constexpr int NTOK = Bb * S;        // 2048
constexpr int NSLOT = NTOK * 2;     // 4096 (top-2)
constexpr float EPSLN = 1e-5f;

typedef __attribute__((ext_vector_type(4))) float f32x4;
typedef __attribute__((ext_vector_type(8))) short s16x8;

#define DEVI __device__ __forceinline__

DEVI float bf2f(short u) {
  union { float f; uint32_t i; } c; c.i = ((uint32_t)(uint16_t)u) << 16; return c.f;
}
DEVI short f2bf(float f) {
  union { float f; uint32_t i; } c; c.f = f;
  uint32_t x = c.i;
  uint32_t r = (x + 0x7fffu + ((x >> 16) & 1u)) >> 16;  // RNE
  return (short)r;
}

DEVI void gload16(const void* g, void* l) {
  __builtin_amdgcn_global_load_lds(g, l, 16, 0, 0);
}

DEVI float gelu1(float g) { return 0.5f * g * (1.f + erff(g * 0.70710678118f)); }

// ---------------- small kernels ----------------
__global__ void k_f32_to_bf16(const float* __restrict__ in, short* __restrict__ out, long n4) {
  long i = (long)blockIdx.x * blockDim.x + threadIdx.x;
  if (i >= n4) return;
  long base = i * 4;
  f32x4 v = *(const f32x4*)(in + base);
  short4 o;
  o.x = f2bf(v.x); o.y = f2bf(v.y); o.z = f2bf(v.z); o.w = f2bf(v.w);
  *(short4*)(out + base) = o;
}

// in  f32 [batch][R][C]  ->  out bf16 [batch][C][R]
__global__ void k_transpose_bf16(const float* __restrict__ in, short* __restrict__ out,
                                 int R, int C, long inBS, long outBS) {
  __shared__ float tile[32][33];
  const float* src = in + (size_t)blockIdx.z * inBS;
  short* dst = out + (size_t)blockIdx.z * outBS;
  int r0 = blockIdx.y * 32, c0 = blockIdx.x * 32;
  int tx = threadIdx.x, ty = threadIdx.y;
#pragma unroll
  for (int i = 0; i < 32; i += 8) {
    int r = r0 + ty + i, c = c0 + tx;
    if (r < R && c < C) tile[ty + i][tx] = src[(size_t)r * C + c];
  }
  __syncthreads();
#pragma unroll
  for (int i = 0; i < 32; i += 8) {
    int c = c0 + ty + i, r = r0 + tx;
    if (r < R && c < C) dst[(size_t)c * R + r] = f2bf(tile[tx][ty + i]);
  }
}

// in f32 [batch][R][C] -> hi/lo bf16 [batch][C][R]
__global__ void k_transpose_split(const float* __restrict__ in, short* __restrict__ oh,
                                  short* __restrict__ ol, int R, int C, long inBS,
                                  long outBS) {
  __shared__ float tile[32][33];
  const float* src = in + (size_t)blockIdx.z * inBS;
  short* dh = oh + (size_t)blockIdx.z * outBS;
  short* dl = ol + (size_t)blockIdx.z * outBS;
  int r0 = blockIdx.y * 32, c0 = blockIdx.x * 32;
  int tx = threadIdx.x, ty = threadIdx.y;
#pragma unroll
  for (int i = 0; i < 32; i += 8) {
    int r = r0 + ty + i, c = c0 + tx;
    if (r < R && c < C) tile[ty + i][tx] = src[(size_t)r * C + c];
  }
  __syncthreads();
#pragma unroll
  for (int i = 0; i < 32; i += 8) {
    int c = c0 + ty + i, r = r0 + tx;
    if (r < R && c < C) {
      float v = tile[tx][ty + i];
      short hi = f2bf(v);
      short lo = f2bf(v - bf2f(hi));
      dh[(size_t)c * R + r] = hi;
      dl[(size_t)c * R + r] = lo;
    }
  }
}

// in f32 [R][C] -> 3-split bf16 [C][R]   (single matrix)
__global__ void k_transpose_split3(const float* __restrict__ in, short* __restrict__ o0,
                                   short* __restrict__ o1, short* __restrict__ o2,
                                   int R, int C) {
  __shared__ float tile[32][33];
  int r0 = blockIdx.y * 32, c0 = blockIdx.x * 32;
  int tx = threadIdx.x, ty = threadIdx.y;
#pragma unroll
  for (int i = 0; i < 32; i += 8) {
    int r = r0 + ty + i, c = c0 + tx;
    if (r < R && c < C) tile[ty + i][tx] = in[(size_t)r * C + c];
  }
  __syncthreads();
#pragma unroll
  for (int i = 0; i < 32; i += 8) {
    int c = c0 + ty + i, r = r0 + tx;
    if (r < R && c < C) {
      float v = tile[tx][ty + i];
      short t0 = f2bf(v);
      float rr = v - bf2f(t0);
      short t1 = f2bf(rr);
      short t2 = f2bf(rr - bf2f(t1));
      o0[(size_t)c * R + r] = t0;
      o1[(size_t)c * R + r] = t1;
      o2[(size_t)c * R + r] = t2;
    }
  }
}

// batched QKV weight transpose+split3: z=0,1,2 selects Wq/Wk/Wv (HxH each)
__global__ void k_wqkv_t3(const float* __restrict__ Wq, const float* __restrict__ Wk,
                          const float* __restrict__ Wv, short* __restrict__ o0,
                          short* __restrict__ o1, short* __restrict__ o2) {
  __shared__ float tile[32][33];
  const int zz = blockIdx.z;
  const float* in = (zz == 0) ? Wq : (zz == 1) ? Wk : Wv;
  const size_t doff = (size_t)zz * H * H;
  int r0 = blockIdx.y * 32, c0 = blockIdx.x * 32;
  int tx = threadIdx.x, ty = threadIdx.y;
#pragma unroll
  for (int i = 0; i < 32; i += 8) {
    int r = r0 + ty + i, c = c0 + tx;
    tile[ty + i][tx] = in[(size_t)r * H + c];
  }
  __syncthreads();
#pragma unroll
  for (int i = 0; i < 32; i += 8) {
    int c = c0 + ty + i, r = r0 + tx;
    float v = tile[tx][ty + i];
    short t0 = f2bf(v);
    float rr = v - bf2f(t0);
    short t1 = f2bf(rr);
    short t2 = f2bf(rr - bf2f(t1));
    o0[doff + (size_t)c * H + r] = t0;
    o1[doff + (size_t)c * H + r] = t1;
    o2[doff + (size_t)c * H + r] = t2;
  }
}

__global__ void k_bqkv(const float* __restrict__ bq, const float* __restrict__ bk,
                       const float* __restrict__ bv, float* __restrict__ bqkv) {
  int i = blockIdx.x * blockDim.x + threadIdx.x;
  if (i >= L * 3 * H) return;
  int l = i / (3 * H), j = i % (3 * H);
  float v = (j < H) ? bq[l * H + j] : (j < 2 * H) ? bk[l * H + j - H] : bv[l * H + j - 2 * H];
  bqkv[i] = v;
}

__global__ void k_ropetab(float* __restrict__ cosT, float* __restrict__ sinT) {
  int i = blockIdx.x * blockDim.x + threadIdx.x;
  if (i >= S * (HD / 2)) return;
  int s = i / 32, d = i % 32;
  float invf = powf(10000.f, -(2.f * d) / (float)HD);
  float ang = (float)s * invf;
  cosT[i] = cosf(ang);
  sinT[i] = sinf(ang);
}

__global__ void k_embed(const int* __restrict__ ids, const float* __restrict__ emb,
                        float* __restrict__ x) {
  int idx = blockIdx.x * blockDim.x + threadIdx.x;  // NTOK*(H/4)
  int row = idx / (H / 4), c4 = idx % (H / 4);
  if (row >= NTOK) return;
  int t = ids[row];
  ((f32x4*)(x + (size_t)row * H))[c4] = ((const f32x4*)(emb + (size_t)t * H))[c4];
}

// ---------------- layernorm with fused output formats ----------------
// OUT 1: split3 -> s0,s1,s2        OUT 2: f32 of + split2 -> s0,s1
// OUT 3: f32 of + bf16 -> s0       OUT 4: bf16 -> s0
template <int OUT>
__global__ void k_layernorm(const float* __restrict__ x, const float* __restrict__ w,
                            const float* __restrict__ b, float* __restrict__ of,
                            short* __restrict__ s0, short* __restrict__ s1,
                            short* __restrict__ s2) {
  int row = blockIdx.x * (blockDim.x >> 6) + (threadIdx.x >> 6);
  int lane = threadIdx.x & 63;
  if (row >= NTOK) return;
  const float* xr = x + (size_t)row * H;
  float v[12], s = 0.f, s2s = 0.f;
#pragma unroll
  for (int j = 0; j < 12; j++) { float t = xr[lane + j * 64]; v[j] = t; s += t; s2s += t * t; }
#pragma unroll
  for (int off = 32; off; off >>= 1) { s += __shfl_xor(s, off); s2s += __shfl_xor(s2s, off); }
  float m = s / (float)H;
  float var = s2s / (float)H - m * m;
  float rs = 1.f / sqrtf(var + EPSLN);
#pragma unroll
  for (int j = 0; j < 12; j++) {
    int c = lane + j * 64;
    float val = (v[j] - m) * rs * w[c] + b[c];
    size_t idx = (size_t)row * H + c;
    if (OUT == 1) {
      short t0 = f2bf(val);
      float rr = val - bf2f(t0);
      short t1 = f2bf(rr);
      short t2 = f2bf(rr - bf2f(t1));
      s0[idx] = t0; s1[idx] = t1; s2[idx] = t2;
    } else if (OUT == 2) {
      of[idx] = val;
      short hi = f2bf(val);
      s0[idx] = hi; s1[idx] = f2bf(val - bf2f(hi));
    } else if (OUT == 3) {
      of[idx] = val;
      s0[idx] = f2bf(val);
    } else {
      s0[idx] = f2bf(val);
    }
  }
}

// ---------------- softmax over hi/lo bf16 scores, in place -------------------
__global__ void k_softmax2(short* __restrict__ p0, short* __restrict__ p1) {
  int row = blockIdx.x * 4 + (threadIdx.x >> 6);  // B*NH*S rows
  int lane = threadIdx.x & 63;
  s16x8* r0 = (s16x8*)(p0 + (size_t)row * S + lane * 16);
  s16x8* r1 = (s16x8*)(p1 + (size_t)row * S + lane * 16);
  s16x8 h0 = r0[0], h1 = r0[1];
  s16x8 l0 = r1[0], l1 = r1[1];
  float v[16];
#pragma unroll
  for (int j = 0; j < 8; j++) {
    v[j] = bf2f(h0[j]) + bf2f(l0[j]);
    v[8 + j] = bf2f(h1[j]) + bf2f(l1[j]);
  }
  float mx = -3e38f;
#pragma unroll
  for (int j = 0; j < 16; j++) mx = fmaxf(mx, v[j]);
#pragma unroll
  for (int off = 32; off; off >>= 1) mx = fmaxf(mx, __shfl_xor(mx, off));
  float sum = 0.f;
#pragma unroll
  for (int j = 0; j < 16; j++) { v[j] = expf(v[j] - mx); sum += v[j]; }
#pragma unroll
  for (int off = 32; off; off >>= 1) sum += __shfl_xor(sum, off);
  float inv = 1.f / sum;
#pragma unroll
  for (int j = 0; j < 16; j++) v[j] *= inv;
  s16x8 oh0, oh1, ol0, ol1;
#pragma unroll
  for (int j = 0; j < 8; j++) {
    short hi = f2bf(v[j]);
    oh0[j] = hi; ol0[j] = f2bf(v[j] - bf2f(hi));
    short hi2 = f2bf(v[8 + j]);
    oh1[j] = hi2; ol1[j] = f2bf(v[8 + j] - bf2f(hi2));
  }
  r0[0] = oh0; r0[1] = oh1;
  r1[0] = ol0; r1[1] = ol1;
}

// ---------------- router (f32 h input -> exact top-2) ----------------
__global__ void k_router(const float* __restrict__ h, const float* __restrict__ Wr,
                         const float* __restrict__ br, float* __restrict__ sel_w,
                         int* __restrict__ sel_e, int* __restrict__ counts) {
  int tok = blockIdx.x * (blockDim.x >> 6) + (threadIdx.x >> 6);
  int lane = threadIdx.x & 63;
  if (tok >= NTOK) return;
  const float* hr = h + (size_t)tok * H;
  float acc[8] = {0, 0, 0, 0, 0, 0, 0, 0};
  for (int i = lane; i < H; i += 64) {
    float hv = hr[i];
    const f32x4* w4 = (const f32x4*)(Wr + (size_t)i * E);
    f32x4 a = w4[0], b = w4[1];
    acc[0] += hv * a.x; acc[1] += hv * a.y; acc[2] += hv * a.z; acc[3] += hv * a.w;
    acc[4] += hv * b.x; acc[5] += hv * b.y; acc[6] += hv * b.z; acc[7] += hv * b.w;
  }
#pragma unroll
  for (int off = 32; off; off >>= 1)
#pragma unroll
    for (int e = 0; e < 8; e++) acc[e] += __shfl_xor(acc[e], off);
  if (lane == 0) {
    float lg[8], m = -3e38f;
#pragma unroll
    for (int e = 0; e < 8; e++) { lg[e] = acc[e] + br[e]; m = fmaxf(m, lg[e]); }
    float sum = 0.f;
#pragma unroll
    for (int e = 0; e < 8; e++) { lg[e] = expf(lg[e] - m); sum += lg[e]; }
    float inv = 1.f / sum;
#pragma unroll
    for (int e = 0; e < 8; e++) lg[e] *= inv;
    int i1 = 0;
#pragma unroll
    for (int e = 1; e < 8; e++) if (lg[e] > lg[i1]) i1 = e;
    int i2 = (i1 == 0) ? 1 : 0;
#pragma unroll
    for (int e = 0; e < 8; e++) if (e != i1 && lg[e] > lg[i2]) i2 = e;
    float p1 = lg[i1], p2 = lg[i2];
    float ws = p1 + p2 + 1e-9f;
    sel_e[tok * 2] = i1; sel_e[tok * 2 + 1] = i2;
    sel_w[tok * 2] = p1 / ws; sel_w[tok * 2 + 1] = p2 / ws;
    atomicAdd(counts + i1, 1);
    atomicAdd(counts + i2, 1);
  }
}

__global__ void k_offsets(const int* __restrict__ counts, int* __restrict__ offs) {
  if (threadIdx.x == 0) {
    int a = 0;
    for (int e = 0; e < E; e++) { offs[e] = a; a += counts[e]; }
    offs[E] = a;
  }
}

__global__ void k_scatter(const int* __restrict__ sel_e, const int* __restrict__ offs,
                          int* __restrict__ cursor, int* __restrict__ tok_list,
                          int* __restrict__ slot_of) {
  int tok = blockIdx.x * blockDim.x + threadIdx.x;
  if (tok >= NTOK) return;
  for (int k = 0; k < 2; k++) {
    int e = sel_e[tok * 2 + k];
    int pos = atomicAdd(cursor + e, 1);
    int g = offs[e] + pos;
    tok_list[g] = tok;
    slot_of[tok * 2 + k] = g;
  }
}

// ff = sum_k w_k * (oe[slot_k] + b2[e_k]); x += ff
__global__ void k_combine(const float* __restrict__ oe, const float* __restrict__ sel_w,
                          const int* __restrict__ slot_of, const int* __restrict__ sel_e,
                          const float* __restrict__ b2, float* __restrict__ x) {
  int idx = blockIdx.x * blockDim.x + threadIdx.x;  // NTOK*(H/4)
  if (idx >= NTOK * (H / 4)) return;
  int tok = idx / (H / 4), c4 = idx % (H / 4);
  float w0 = sel_w[tok * 2], w1 = sel_w[tok * 2 + 1];
  int s0 = slot_of[tok * 2], s1 = slot_of[tok * 2 + 1];
  int e0 = sel_e[tok * 2], e1 = sel_e[tok * 2 + 1];
  f32x4 a = ((const f32x4*)(oe + (size_t)s0 * H))[c4];
  f32x4 b = ((const f32x4*)(oe + (size_t)s1 * H))[c4];
  f32x4 ba = ((const f32x4*)(b2 + (size_t)e0 * H))[c4];
  f32x4 bb = ((const f32x4*)(b2 + (size_t)e1 * H))[c4];
  f32x4* xp = (f32x4*)(x + (size_t)tok * H) + c4;
  *xp = *xp + w0 * (a + ba) + w1 * (b + bb);
}

// ---------------- split-MFMA GEMM: C = (ΣA_s)·(ΣB_s)^T, products i+j<SP -----
// SP=2: 3 MFMAs/frag; SP=3: 6 MFMAs/frag.
// MODE 0: f32 out (+bias opt)   1: f32 out = res + acc + bias
// MODE 6: gelu(acc+bias) -> split2 bf16 (Cp,Cp2)
// MODE 7: acc*alpha + causal -> split2 bf16 (Cp,Cp2); tiles with tn>tm are
//         fully masked -> write split(-1e9) and skip all compute (softmax
//         output is bit-identical: exp underflows to 0 either way).
// MODE 8: acc -> split3 bf16 (Cp,Cp2,Cp3); K capped at (tm+1)*128 (P rows
//         beyond the causal boundary are exactly +0 -> contribution exact 0).
// MODE 9: QKV fused: bias + RoPE + split3(q->Cp..3, k->K0..2) / split2(v->V0,V1)
template <int SP, int MODE, bool GATHER>
__global__ __launch_bounds__(256, 2) void k_bgemmS(
    const short* __restrict__ A0, const short* __restrict__ A1, const short* __restrict__ A2,
    long sAz, int lda,
    const short* __restrict__ B0, const short* __restrict__ B1, const short* __restrict__ B2,
    long sBz, int ldb,
    void* __restrict__ Cp, void* __restrict__ Cp2, void* __restrict__ Cp3,
    short* __restrict__ K0, short* __restrict__ K1, short* __restrict__ K2,
    short* __restrict__ V0, short* __restrict__ V1,
    const float* __restrict__ cT, const float* __restrict__ sT,
    int zdiv, long sChi, long sClo, int ldc,
    const float* __restrict__ res, const float* __restrict__ bias, long sBias,
    int M, int N, int K,
    const int* __restrict__ d_counts, const int* __restrict__ d_offs,
    const int* __restrict__ gidx, float alpha) {
  const int z = blockIdx.z;
  const int Meff = d_counts ? d_counts[z] : M;
  const int tm = blockIdx.y;
  if (tm * 128 >= Meff) return;
  const int tn = blockIdx.x;
  const int row_base = d_offs ? d_offs[z] : 0;

  __shared__ short Ab[SP][128 * 32];
  __shared__ short Bb2[SP][128 * 32];

  const int tid = threadIdx.x;
  const int lane = tid & 63;
  const int w = tid >> 6;

  const int wr = (w >> 1) * 64;
  const int wc = (w & 1) * 64;
  const int r16 = lane & 15;
  const int kb4 = lane >> 4;
  const int q4 = lane >> 4;

  if (MODE == 7 && tn > tm) {
    // fully causal-masked tile: emit split(-1e9) without any compute
    const short mhi = f2bf(-1e9f);
    const short mlo = f2bf(-1e9f - bf2f(mhi));
    const long out_off = (long)(z / zdiv) * sChi + (long)(z % zdiv) * sClo;
#pragma unroll
    for (int mi = 0; mi < 4; ++mi) {
#pragma unroll
      for (int j = 0; j < 4; ++j) {
        const int lrow = tm * 128 + wr + mi * 16 + q4 * 4 + j;
        const long rbase = out_off + (long)lrow * ldc;
#pragma unroll
        for (int ni = 0; ni < 4; ++ni) {
          const long idx = rbase + tn * 128 + wc + ni * 16 + r16;
          ((short*)Cp)[idx] = mhi;
          ((short*)Cp2)[idx] = mlo;
        }
      }
    }
    return;
  }

  const short* APz[3];
  const short* BPz[3];
  APz[0] = A0 + (size_t)z * sAz;
  APz[1] = A1 + (size_t)z * sAz;
  APz[2] = (SP > 2) ? (A2 + (size_t)z * sAz) : APz[0];
  BPz[0] = B0 + (size_t)z * sBz;
  BPz[1] = B1 + (size_t)z * sBz;
  BPz[2] = (SP > 2) ? (B2 + (size_t)z * sBz) : BPz[0];

  size_t aOff[2], bOff[2];
#pragma unroll
  for (int i = 0; i < 2; ++i) {
    const int srow = i * 64 + (tid >> 2);
    const int kb = (tid & 3) ^ (srow & 3);  // pre-swizzled source (involution)
    int lrow = tm * 128 + srow;
    if (lrow > Meff - 1) lrow = Meff - 1;
    int ar = row_base + lrow;
    if (GATHER) ar = gidx[ar];
    aOff[i] = (size_t)ar * lda + kb * 8;
    int bcol = tn * 128 + srow;
    if (bcol > N - 1) bcol = N - 1;
    bOff[i] = (size_t)bcol * ldb + kb * 8;
  }

  f32x4 acc[4][4];
#pragma unroll
  for (int a = 0; a < 4; ++a)
#pragma unroll
    for (int b = 0; b < 4; ++b) acc[a][b] = {0.f, 0.f, 0.f, 0.f};

  const int swz = (kb4 ^ (r16 & 3)) * 8;
  int aoff[4], boff[4];
#pragma unroll
  for (int i = 0; i < 4; ++i) {
    aoff[i] = (wr + i * 16 + r16) * 32 + swz;
    boff[i] = (wc + i * 16 + r16) * 32 + swz;
  }

  // PV: keys beyond causal boundary have P == +0.0 exactly -> skip (exact).
  const int Keff = (MODE == 8) ? (((tm + 1) * 128 < K) ? (tm + 1) * 128 : K) : K;

  for (int k0 = 0; k0 < Keff; k0 += 32) {
#pragma unroll
    for (int s = 0; s < SP; ++s) {
      gload16(APz[s] + aOff[0], (char*)(&Ab[s][0]) + w * 1024);
      gload16(APz[s] + aOff[1], (char*)(&Ab[s][0]) + 4096 + w * 1024);
      gload16(BPz[s] + bOff[0], (char*)(&Bb2[s][0]) + w * 1024);
      gload16(BPz[s] + bOff[1], (char*)(&Bb2[s][0]) + 4096 + w * 1024);
    }
    aOff[0] += 32; aOff[1] += 32; bOff[0] += 32; bOff[1] += 32;
    __syncthreads();
    s16x8 af[SP][4], bf[SP][4];
#pragma unroll
    for (int s = 0; s < SP; ++s)
#pragma unroll
      for (int i = 0; i < 4; ++i) {
        af[s][i] = *(const s16x8*)(&Ab[s][aoff[i]]);
        bf[s][i] = *(const s16x8*)(&Bb2[s][boff[i]]);
      }
#pragma unroll
    for (int mi = 0; mi < 4; ++mi)
#pragma unroll
      for (int ni = 0; ni < 4; ++ni) {
        f32x4 a = acc[mi][ni];
#pragma unroll
        for (int si = 0; si < SP; ++si)
#pragma unroll
          for (int sj = 0; sj < SP - si; ++sj)
            a = __builtin_amdgcn_mfma_f32_16x16x32_bf16(af[si][mi], bf[sj][ni], a, 0, 0, 0);
        acc[mi][ni] = a;
      }
    __syncthreads();
  }

  const float* bz = bias ? (bias + (size_t)z * sBias) : nullptr;
  float bvv[4];
  int gco[4];
#pragma unroll
  for (int ni = 0; ni < 4; ++ni) {
    gco[ni] = tn * 128 + wc + ni * 16 + r16;
    bvv[ni] = (bz && gco[ni] < N) ? bz[gco[ni]] : 0.f;
  }

  if (MODE == 9) {
    // QKV fused epilogue: cols = [q(768) | k(768) | v(768)], heads of 64.
    const int sec_base = tn * 128 + wc;     // multiple of 64, aligned to sections
    const int sec = sec_base / H;           // 0=q, 1=k, 2=v
    const int hh = (sec_base % H) / HD;
#pragma unroll
    for (int mi = 0; mi < 4; ++mi) {
#pragma unroll
      for (int j = 0; j < 4; ++j) {
        const int row = tm * 128 + wr + mi * 16 + q4 * 4 + j;   // token
        const int ss = row & (S - 1);
        const long zz = (long)((row >> 10) * NHd + hh);
#pragma unroll
        for (int ni = 0; ni < 2; ++ni) {
          const int d = ni * 16 + r16;                          // 0..31
          float a1 = acc[mi][ni][j] + bvv[ni];
          float a2 = acc[mi][ni + 2][j] + bvv[ni + 2];
          if (sec < 2) {
            float cc = cT[ss * 32 + d], sn = sT[ss * 32 + d];
            float r1 = a1 * cc - a2 * sn;
            float r2 = a2 * cc + a1 * sn;
            const long bi = (zz * S + ss) * HD + d;
            short* d0 = (sec == 0) ? (short*)Cp : K0;
            short* d1 = (sec == 0) ? (short*)Cp2 : K1;
            short* d2 = (sec == 0) ? (short*)Cp3 : K2;
            short t0 = f2bf(r1); float rr = r1 - bf2f(t0);
            short t1 = f2bf(rr); short t2 = f2bf(rr - bf2f(t1));
            d0[bi] = t0; d1[bi] = t1; d2[bi] = t2;
            t0 = f2bf(r2); rr = r2 - bf2f(t0);
            t1 = f2bf(rr); t2 = f2bf(rr - bf2f(t1));
            d0[bi + 32] = t0; d1[bi + 32] = t1; d2[bi + 32] = t2;
          } else {
            const long vb1 = zz * HD * S + (long)d * S + ss;
            short hv = f2bf(a1);
            V0[vb1] = hv; V1[vb1] = f2bf(a1 - bf2f(hv));
            const long vb2 = vb1 + 32L * S;
            hv = f2bf(a2);
            V0[vb2] = hv; V1[vb2] = f2bf(a2 - bf2f(hv));
          }
        }
      }
    }
    return;
  }

  const long out_off = (long)(z / zdiv) * sChi + (long)(z % zdiv) * sClo;
#pragma unroll
  for (int mi = 0; mi < 4; ++mi) {
#pragma unroll
    for (int j = 0; j < 4; ++j) {
      const int lrow = tm * 128 + wr + mi * 16 + q4 * 4 + j;
      if (lrow >= Meff) continue;
      const long rbase = out_off + (long)(row_base + lrow) * ldc;
#pragma unroll
      for (int ni = 0; ni < 4; ++ni) {
        if (gco[ni] >= N) continue;
        const float v = acc[mi][ni][j];
        const long idx = rbase + gco[ni];
        if (MODE == 0) {
          ((float*)Cp)[idx] = v + bvv[ni];
        } else if (MODE == 1) {
          ((float*)Cp)[idx] = res[idx] + v + bvv[ni];
        } else if (MODE == 6) {
          float g = gelu1(v + bvv[ni]);
          short hi = f2bf(g);
          ((short*)Cp)[idx] = hi;
          ((short*)Cp2)[idx] = f2bf(g - bf2f(hi));
        } else if (MODE == 7) {
          float g = v * alpha + ((gco[ni] > lrow) ? -1e9f : 0.f);
          short hi = f2bf(g);
          ((short*)Cp)[idx] = hi;
          ((short*)Cp2)[idx] = f2bf(g - bf2f(hi));
        } else if (MODE == 8) {
          float g = v + bvv[ni];
          short t0 = f2bf(g); float rr = g - bf2f(t0);
          short t1 = f2bf(rr); short t2 = f2bf(rr - bf2f(t1));
          ((short*)Cp)[idx] = t0;
          ((short*)Cp2)[idx] = t1;
          ((short*)Cp3)[idx] = t2;
        }
      }
    }
  }
}

template <int SP, int MODE, bool GATHER>
static void bgemmS(hipStream_t st, const short* A0, const short* A1, const short* A2, long sAz,
                   int lda, const short* B0, const short* B1, const short* B2, long sBz,
                   int ldb, void* C, void* C2, void* C3, int zdiv, long sChi, long sClo,
                   int ldc, const float* res, const float* bias, long sBias, int M, int N,
                   int K, int nz, const int* cnts, const int* offs_, const int* gat,
                   float alpha, short* K0 = nullptr, short* K1 = nullptr, short* K2 = nullptr,
                   short* V0 = nullptr, short* V1 = nullptr, const float* cT = nullptr,
                   const float* sT = nullptr) {
  dim3 g((N + 127) / 128, (M + 127) / 128, nz);
  k_bgemmS<SP, MODE, GATHER><<<g, 256, 0, st>>>(A0, A1, A2, sAz, lda, B0, B1, B2, sBz, ldb, C,
                                                C2, C3, K0, K1, K2, V0, V1, cT, sT, zdiv, sChi,
                                                sClo, ldc, res, bias, sBias, M, N, K, cnts,
                                                offs_, gat, alpha);
}

// ---------------- plain bf16 MFMA GEMM, BK=64 (l1 MoE + logits) --------------
// R10-proven structure: single-buffered, 32 KB LDS, XOR-swizzled staging.
// MODE 0: f32 out (+bias opt)   4: bf16 out = gelu(acc + bias)
// NSWZ: N-major + bijective XCD-chunk swizzle (B-tile L2 locality).
template <int MODE, bool GATHER, bool NSWZ>
__global__ __launch_bounds__(256, 2) void k_bgemm(
    const short* __restrict__ A, long sAz, int lda,
    const short* __restrict__ Bt, long sBz, int ldb,
    void* __restrict__ Cp, int zdiv, long sChi, long sClo, int ldc,
    const float* __restrict__ bias, long sBias,
    int M, int N, int K,
    const int* __restrict__ d_counts, const int* __restrict__ d_offs,
    const int* __restrict__ gidx) {
  const int z = blockIdx.z;
  const int Meff = d_counts ? d_counts[z] : M;
  int tm, tn;
  if (NSWZ) {
    const int bid = blockIdx.y * gridDim.x + blockIdx.x;
    const int nwg = gridDim.x * gridDim.y;
    const int q = nwg >> 3, r = nwg & 7;
    const int xcd = bid & 7, ix = bid >> 3;
    const int wg = (xcd < r) ? (xcd * (q + 1) + ix) : (r * (q + 1) + (xcd - r) * q + ix);
    tn = wg / gridDim.y;   // N-major: consecutive wg share tn
    tm = wg % gridDim.y;
  } else {
    tm = blockIdx.y;
    tn = blockIdx.x;
  }
  if (tm * 128 >= Meff) return;
  const int row_base = d_offs ? d_offs[z] : 0;

  __shared__ short Abuf[128 * 64];   // 16 KB
  __shared__ short Bbuf[128 * 64];   // 16 KB

  const int tid = threadIdx.x;
  const int lane = tid & 63;
  const int w = tid >> 6;

  const short* Az = A + (size_t)z * sAz;
  const short* Bz = Bt + (size_t)z * sBz;

  // staging: chunk c = w*4+i covers LDS rows c*8..c*8+7; lane -> row c*8+(lane>>3),
  // k-unit lane&7; source k pre-swizzled by (row&7)^unit (involution, rule #21).
  const int swzS = ((lane >> 3) ^ (lane & 7)) * 8;
  const short* aSrc[4];
  const short* bSrc[4];
#pragma unroll
  for (int i = 0; i < 4; ++i) {
    const int rin = (w * 4 + i) * 8 + (lane >> 3);  // 0..127
    int lrow = tm * 128 + rin;
    if (lrow > Meff - 1) lrow = Meff - 1;
    int ar = row_base + lrow;
    if (GATHER) ar = gidx[ar];
    aSrc[i] = Az + (size_t)ar * lda + swzS;
    int bcol = tn * 128 + rin;
    if (bcol > N - 1) bcol = N - 1;
    bSrc[i] = Bz + (size_t)bcol * ldb + swzS;
  }

  f32x4 acc[4][4];
#pragma unroll
  for (int a = 0; a < 4; ++a)
#pragma unroll
    for (int b = 0; b < 4; ++b) acc[a][b] = {0.f, 0.f, 0.f, 0.f};

  const int wr = (w >> 1) * 64;
  const int wc = (w & 1) * 64;
  const int r16 = lane & 15;
  const int kb4 = lane >> 4;
  int aoff[4][2], boff[4][2];
#pragma unroll
  for (int i = 0; i < 4; ++i) {
#pragma unroll
    for (int kw = 0; kw < 2; ++kw) {
      const int sw = ((r16 & 7) ^ (kw * 4 + kb4)) * 8;
      aoff[i][kw] = (wr + i * 16 + r16) * 64 + sw;
      boff[i][kw] = (wc + i * 16 + r16) * 64 + sw;
    }
  }

  for (int k0 = 0; k0 < K; k0 += 64) {
#pragma unroll
    for (int i = 0; i < 4; ++i) gload16(aSrc[i], (char*)Abuf + (w * 4 + i) * 1024);
#pragma unroll
    for (int i = 0; i < 4; ++i) gload16(bSrc[i], (char*)Bbuf + (w * 4 + i) * 1024);
#pragma unroll
    for (int i = 0; i < 4; ++i) { aSrc[i] += 64; bSrc[i] += 64; }
    __syncthreads();
#pragma unroll
    for (int kw = 0; kw < 2; ++kw) {
      s16x8 af[4], bf[4];
#pragma unroll
      for (int i = 0; i < 4; ++i) {
        af[i] = *(const s16x8*)(Abuf + aoff[i][kw]);
        bf[i] = *(const s16x8*)(Bbuf + boff[i][kw]);
      }
#pragma unroll
      for (int mi = 0; mi < 4; ++mi)
#pragma unroll
        for (int ni = 0; ni < 4; ++ni)
          acc[mi][ni] =
              __builtin_amdgcn_mfma_f32_16x16x32_bf16(af[mi], bf[ni], acc[mi][ni], 0, 0, 0);
    }
    __syncthreads();
  }

  const long out_off = (long)(z / zdiv) * sChi + (long)(z % zdiv) * sClo;
  const float* bz = bias ? (bias + (size_t)z * sBias) : nullptr;
  const int q4 = lane >> 4;
  float bvv[4];
  int gco[4];
#pragma unroll
  for (int ni = 0; ni < 4; ++ni) {
    gco[ni] = tn * 128 + wc + ni * 16 + r16;
    bvv[ni] = (bz && gco[ni] < N) ? bz[gco[ni]] : 0.f;
  }
#pragma unroll
  for (int mi = 0; mi < 4; ++mi) {
#pragma unroll
    for (int j = 0; j < 4; ++j) {
      const int lrow = tm * 128 + wr + mi * 16 + q4 * 4 + j;
      if (lrow >= Meff) continue;
      const long rbase = out_off + (row_base + lrow) * (long)ldc;
#pragma unroll
      for (int ni = 0; ni < 4; ++ni) {
        if (gco[ni] >= N) continue;
        const float v = acc[mi][ni][j];
        if (MODE == 0) {
          ((float*)Cp)[rbase + gco[ni]] = v + bvv[ni];
        } else if (MODE == 4) {
          float g = v + bvv[ni];
          ((short*)Cp)[rbase + gco[ni]] = f2bf(gelu1(g));
        }
      }
    }
  }
}

template <int MODE, bool GATHER, bool NSWZ>
static void bgemm(hipStream_t st, const short* A, long sAz, int lda, const short* Bt, long sBz,
                  int ldb, void* C, int zdiv, long sChi, long sClo, int ldc, const float* bias,
                  long sBias, int M, int N, int K, int nz, const int* cnts, const int* offs_,
                  const int* gat) {
  dim3 g((N + 127) / 128, (M + 127) / 128, nz);
  k_bgemm<MODE, GATHER, NSWZ><<<g, 256, 0, st>>>(A, sAz, lda, Bt, sBz, ldb, C, zdiv, sChi,
                                                 sClo, ldc, bias, sBias, M, N, K, cnts, offs_,
                                                 gat);
}

// ---------------- launch ----------------
extern "C" void kernel_launch(void* const* d_in, const int* in_sizes, int n_in, void* d_out,
                              int out_size, void* d_ws, size_t ws_size, hipStream_t stream) {
  (void)in_sizes; (void)n_in; (void)out_size; (void)ws_size;
  const int*   ids  = (const int*)d_in[0];
  const float* emb  = (const float*)d_in[1];
  const float* ln1w = (const float*)d_in[2];
  const float* ln1b = (const float*)d_in[3];
  const float* ln2w = (const float*)d_in[4];
  const float* ln2b = (const float*)d_in[5];
  const float* lnfw = (const float*)d_in[6];
  const float* lnfb = (const float*)d_in[7];
  const float* Wq = (const float*)d_in[8];
  const float* bq = (const float*)d_in[9];
  const float* Wk = (const float*)d_in[10];
  const float* bk = (const float*)d_in[11];
  const float* Wv = (const float*)d_in[12];
  const float* bv = (const float*)d_in[13];
  const float* Wo = (const float*)d_in[14];
  const float* bo = (const float*)d_in[15];
  const float* Wr = (const float*)d_in[16];
  const float* br = (const float*)d_in[17];
  const float* W1 = (const float*)d_in[18];
  const float* b1 = (const float*)d_in[19];
  const float* W2 = (const float*)d_in[20];
  const float* b2 = (const float*)d_in[21];
  float* out = (float*)d_out;

  char* p = (char*)d_ws;
  auto alloc = [&](size_t bytes) {
    char* r = p;
    p += (bytes + 255) & ~(size_t)255;
    return r;
  };
  short* embB = (short*)alloc((size_t)V * H * 2);               // 77.2 MB
  // big region (100.7 MB), time-shared: attention [p0|p1] vs MoE [R_hi|R_lo]
  char* big = alloc((size_t)Bb * NHd * S * S * 2 * 2);
  short* p0   = (short*)big;
  short* p1   = p0 + (size_t)Bb * NHd * S * S;
  short* R_hi = (short*)big;
  short* R_lo = R_hi + (size_t)E * F * H;
  short* Wb0 = (short*)alloc((size_t)3 * H * H * 2);            // QKV W^T 3-splits
  short* Wb1 = (short*)alloc((size_t)3 * H * H * 2);
  short* Wb2 = (short*)alloc((size_t)3 * H * H * 2);
  short* Wo0 = (short*)alloc((size_t)H * H * 2);                // Wo^T 3-splits
  short* Wo1 = (short*)alloc((size_t)H * H * 2);
  short* Wo2 = (short*)alloc((size_t)H * H * 2);
  float* bqkv = (float*)alloc((size_t)L * 3 * H * 4);
  float* cosT = (float*)alloc((size_t)S * 32 * 4);
  float* sinT = (float*)alloc((size_t)S * 32 * 4);
  float* x    = (float*)alloc((size_t)NTOK * H * 4);
  float* hbuf = (float*)alloc((size_t)NTOK * H * 4);
  short* xb   = (short*)alloc((size_t)NTOK * H * 2);
  short* xb2  = (short*)alloc((size_t)NTOK * H * 2);
  short* h_hi = (short*)alloc((size_t)NTOK * H * 2);
  short* h_lo = (short*)alloc((size_t)NTOK * H * 2);
  short* h30  = (short*)alloc((size_t)NTOK * H * 2);
  short* h31  = (short*)alloc((size_t)NTOK * H * 2);
  short* h32  = (short*)alloc((size_t)NTOK * H * 2);
  short* q30  = (short*)alloc((size_t)NTOK * H * 2);
  short* q31  = (short*)alloc((size_t)NTOK * H * 2);
  short* q32  = (short*)alloc((size_t)NTOK * H * 2);
  short* k30  = (short*)alloc((size_t)NTOK * H * 2);
  short* k31  = (short*)alloc((size_t)NTOK * H * 2);
  short* k32  = (short*)alloc((size_t)NTOK * H * 2);
  short* v20  = (short*)alloc((size_t)NTOK * H * 2);
  short* v21  = (short*)alloc((size_t)NTOK * H * 2);
  short* o30  = (short*)alloc((size_t)NTOK * H * 2);
  short* o31  = (short*)alloc((size_t)NTOK * H * 2);
  short* o32  = (short*)alloc((size_t)NTOK * H * 2);
  // union region (63.1 MB): act_hi+act_lo (l0) / act_b (l1) + oe
  char* uni = alloc((size_t)NSLOT * F * 4 + (size_t)NSLOT * H * 4);
  short* act_hi = (short*)uni;
  short* act_lo = (short*)(uni + (size_t)NSLOT * F * 2);
  short* act_b  = (short*)uni;
  float* oe     = (float*)(uni + (size_t)NSLOT * F * 4);
  int* counts  = (int*)alloc(2 * E * 4);
  int* cursor  = counts + E;
  int* offs    = (int*)alloc((E + 1) * 4);
  int* sel_e   = (int*)alloc((size_t)NTOK * 2 * 4);
  float* sel_w = (float*)alloc((size_t)NTOK * 2 * 4);
  int* slot_of = (int*)alloc((size_t)NTOK * 2 * 4);
  int* tok_lst = (int*)alloc((size_t)NSLOT * 4);

  // ---- prologue ----
  long nEmb4 = (long)V * H / 4;
  k_f32_to_bf16<<<(nEmb4 + 255) / 256, 256, 0, stream>>>(emb, embB, nEmb4);
  k_bqkv<<<(L * 3 * H + 255) / 256, 256, 0, stream>>>(bq, bk, bv, bqkv);
  k_ropetab<<<(S * 32 + 255) / 256, 256, 0, stream>>>(cosT, sinT);
  k_embed<<<(NTOK * (H / 4) + 255) / 256, 256, 0, stream>>>(ids, emb, x);

  dim3 tb(32, 8);
  const dim3 tHH(H / 32, H / 32, 1);

  for (int l = 0; l < L; l++) {
    // --- attention (bf16x6 split-MFMA; upstream of routers) ---
    k_layernorm<1><<<NTOK / 4, 256, 0, stream>>>(x, ln1w + l * H, ln1b + l * H, nullptr, h30,
                                                 h31, h32);
    k_wqkv_t3<<<dim3(H / 32, H / 32, 3), tb, 0, stream>>>(
        Wq + (size_t)l * H * H, Wk + (size_t)l * H * H, Wv + (size_t)l * H * H, Wb0, Wb1, Wb2);
    // QKV fused with bias+RoPE+splits (MODE 9)
    bgemmS<3, 9, false>(stream, h30, h31, h32, 0, H, Wb0, Wb1, Wb2, 0, H, q30, q31, q32, 1, 0,
                        0, 0, nullptr, bqkv + l * 3 * H, 0, NTOK, 3 * H, H, 1, nullptr,
                        nullptr, nullptr, 1.f, k30, k31, k32, v20, v21, cosT, sinT);
    // QK^T: scale+causal -> hi/lo bf16 scores (fully-masked tiles skipped)
    bgemmS<3, 7, false>(stream, q30, q31, q32, (long)S * HD, HD, k30, k31, k32, (long)S * HD,
                        HD, p0, p1, nullptr, 1, (long)S * S, 0, S, nullptr, nullptr, 0, S, S,
                        HD, Bb * NHd, nullptr, nullptr, nullptr, 0.125f);
    k_softmax2<<<(Bb * NHd * S) / 4, 256, 0, stream>>>(p0, p1);
    // PV -> o split3 (MODE 8; K capped at causal boundary)
    bgemmS<2, 8, false>(stream, p0, p1, nullptr, (long)S * S, S, v20, v21, nullptr,
                        (long)HD * S, S, o30, o31, o32, NHd, (long)S * H, HD, H, nullptr,
                        nullptr, 0, S, HD, S, Bb * NHd, nullptr, nullptr, nullptr, 1.f);
    // Wo: x += o @ Wo + bo
    k_transpose_split3<<<tHH, tb, 0, stream>>>(Wo + (size_t)l * H * H, Wo0, Wo1, Wo2, H, H);
    bgemmS<3, 1, false>(stream, o30, o31, o32, 0, H, Wo0, Wo1, Wo2, 0, H, x, nullptr, nullptr,
                        1, 0, 0, H, x, bo + l * H, 0, NTOK, H, H, 1, nullptr, nullptr, nullptr,
                        1.f);

    // --- MoE ---
    if (l == 0)
      k_layernorm<2><<<NTOK / 4, 256, 0, stream>>>(x, ln2w + l * H, ln2b + l * H, hbuf, h_hi,
                                                   h_lo, nullptr);
    else
      k_layernorm<3><<<NTOK / 4, 256, 0, stream>>>(x, ln2w + l * H, ln2b + l * H, hbuf, xb2,
                                                   nullptr, nullptr);
    hipMemsetAsync(counts, 0, 2 * E * sizeof(int), stream);
    k_router<<<NTOK / 4, 256, 0, stream>>>(hbuf, Wr + (size_t)l * H * E, br + l * E, sel_w,
                                           sel_e, counts);
    k_offsets<<<1, 64, 0, stream>>>(counts, offs);
    k_scatter<<<(NTOK + 255) / 256, 256, 0, stream>>>(sel_e, offs, cursor, tok_lst, slot_of);
    if (l == 0) {
      // bf16x3 split MFMA experts (proven path; p0/p1 dead -> R region free)
      k_transpose_split<<<dim3(F / 32, H / 32, E), tb, 0, stream>>>(
          W1, R_hi, R_lo, H, F, (long)H * F, (long)F * H);
      bgemmS<2, 6, true>(stream, h_hi, h_lo, nullptr, 0, H, R_hi, R_lo, nullptr, (long)F * H,
                         H, act_hi, act_lo, nullptr, 1, 0, 0, F, nullptr, b1, F, NSLOT, F, H,
                         E, counts, offs, tok_lst, 1.f);
      k_transpose_split<<<dim3(H / 32, F / 32, E), tb, 0, stream>>>(
          W2, R_hi, R_lo, F, H, (long)F * H, (long)H * F);
      bgemmS<2, 0, false>(stream, act_hi, act_lo, nullptr, 0, F, R_hi, R_lo, nullptr,
                          (long)H * F, F, oe, nullptr, nullptr, 1, 0, 0, H, nullptr, nullptr,
                          0, NSLOT, H, F, E, counts, offs, nullptr, 1.f);
      k_combine<<<(NTOK * (H / 4) + 255) / 256, 256, 0, stream>>>(oe, sel_w, slot_of, sel_e,
                                                                  b2, x);
    } else {
      // plain bf16 MFMA experts (128-tile BK=64); stage l1 weights
      k_transpose_bf16<<<dim3(F / 32, H / 32, E), tb, 0, stream>>>(
          W1 + (size_t)1 * E * H * F, R_hi, H, F, (long)H * F, (long)F * H);
      k_transpose_bf16<<<dim3(H / 32, F / 32, E), tb, 0, stream>>>(
          W2 + (size_t)1 * E * F * H, R_lo, F, H, (long)F * H, (long)H * F);
      bgemm<4, true, false>(stream, xb2, 0, H, R_hi, (long)F * H, H, act_b, 1, 0, 0, F,
                            b1 + (size_t)l * E * F, F, NSLOT, F, H, E, counts, offs, tok_lst);
      bgemm<0, false, false>(stream, act_b, 0, F, R_lo, (long)H * F, F, oe, 1, 0, 0, H,
                             nullptr, 0, NSLOT, H, F, E, counts, offs, nullptr);
      k_combine<<<(NTOK * (H / 4) + 255) / 256, 256, 0, stream>>>(oe, sel_w, slot_of, sel_e,
                                                                  b2 + (size_t)l * E * H, x);
    }
  }

  // --- final LN + tied logits (BK=64 bf16 MFMA, XCD-chunked N-major) ---
  k_layernorm<4><<<NTOK / 4, 256, 0, stream>>>(x, lnfw, lnfb, nullptr, xb, nullptr, nullptr);
  bgemm<0, false, true>(stream, xb, 0, H, embB, 0, H, out, 1, 0, 0, V, nullptr, 0, NTOK, V, H,
                        1, nullptr, nullptr, nullptr);
}

// Round 14
// 1576.767 us; speedup vs baseline: 1.1219x; 1.0690x over previous
//
#include <hip/hip_runtime.h>
#include <stdint.h>

// ---------------- dims ----------------
constexpr int L = 2, Bb = 2, S = 1024, H = 768, NHd = 12, HD = 64;
constexpr int E = 8, F = 3072, V = 50257;
constexpr int NTOK = Bb * S;        // 2048
constexpr int NSLOT = NTOK * 2;     // 4096 (top-2)
constexpr float EPSLN = 1e-5f;

typedef __attribute__((ext_vector_type(4))) float f32x4;
typedef __attribute__((ext_vector_type(8))) short s16x8;

#define DEVI __device__ __forceinline__

DEVI float bf2f(short u) {
  union { float f; uint32_t i; } c; c.i = ((uint32_t)(uint16_t)u) << 16; return c.f;
}
DEVI short f2bf(float f) {
  union { float f; uint32_t i; } c; c.f = f;
  uint32_t x = c.i;
  uint32_t r = (x + 0x7fffu + ((x >> 16) & 1u)) >> 16;  // RNE
  return (short)r;
}

DEVI void gload16(const void* g, void* l) {
  __builtin_amdgcn_global_load_lds(g, l, 16, 0, 0);
}

DEVI float gelu1(float g) { return 0.5f * g * (1.f + erff(g * 0.70710678118f)); }

// ---------------- small kernels ----------------
__global__ void k_f32_to_bf16(const float* __restrict__ in, short* __restrict__ out, long n4) {
  long i = (long)blockIdx.x * blockDim.x + threadIdx.x;
  if (i >= n4) return;
  long base = i * 4;
  f32x4 v = *(const f32x4*)(in + base);
  short4 o;
  o.x = f2bf(v.x); o.y = f2bf(v.y); o.z = f2bf(v.z); o.w = f2bf(v.w);
  *(short4*)(out + base) = o;
}

// in  f32 [batch][R][C]  ->  out bf16 [batch][C][R]
__global__ void k_transpose_bf16(const float* __restrict__ in, short* __restrict__ out,
                                 int R, int C, long inBS, long outBS) {
  __shared__ float tile[32][33];
  const float* src = in + (size_t)blockIdx.z * inBS;
  short* dst = out + (size_t)blockIdx.z * outBS;
  int r0 = blockIdx.y * 32, c0 = blockIdx.x * 32;
  int tx = threadIdx.x, ty = threadIdx.y;
#pragma unroll
  for (int i = 0; i < 32; i += 8) {
    int r = r0 + ty + i, c = c0 + tx;
    if (r < R && c < C) tile[ty + i][tx] = src[(size_t)r * C + c];
  }
  __syncthreads();
#pragma unroll
  for (int i = 0; i < 32; i += 8) {
    int c = c0 + ty + i, r = r0 + tx;
    if (r < R && c < C) dst[(size_t)c * R + r] = f2bf(tile[tx][ty + i]);
  }
}

// in f32 [batch][R][C] -> hi/lo bf16 [batch][C][R]
__global__ void k_transpose_split(const float* __restrict__ in, short* __restrict__ oh,
                                  short* __restrict__ ol, int R, int C, long inBS,
                                  long outBS) {
  __shared__ float tile[32][33];
  const float* src = in + (size_t)blockIdx.z * inBS;
  short* dh = oh + (size_t)blockIdx.z * outBS;
  short* dl = ol + (size_t)blockIdx.z * outBS;
  int r0 = blockIdx.y * 32, c0 = blockIdx.x * 32;
  int tx = threadIdx.x, ty = threadIdx.y;
#pragma unroll
  for (int i = 0; i < 32; i += 8) {
    int r = r0 + ty + i, c = c0 + tx;
    if (r < R && c < C) tile[ty + i][tx] = src[(size_t)r * C + c];
  }
  __syncthreads();
#pragma unroll
  for (int i = 0; i < 32; i += 8) {
    int c = c0 + ty + i, r = r0 + tx;
    if (r < R && c < C) {
      float v = tile[tx][ty + i];
      short hi = f2bf(v);
      short lo = f2bf(v - bf2f(hi));
      dh[(size_t)c * R + r] = hi;
      dl[(size_t)c * R + r] = lo;
    }
  }
}

// batched QKV weight transpose+split2: z=0,1,2 selects Wq/Wk/Wv (HxH each)
__global__ void k_wqkv_t2(const float* __restrict__ Wq, const float* __restrict__ Wk,
                          const float* __restrict__ Wv, short* __restrict__ o0,
                          short* __restrict__ o1) {
  __shared__ float tile[32][33];
  const int zz = blockIdx.z;
  const float* in = (zz == 0) ? Wq : (zz == 1) ? Wk : Wv;
  const size_t doff = (size_t)zz * H * H;
  int r0 = blockIdx.y * 32, c0 = blockIdx.x * 32;
  int tx = threadIdx.x, ty = threadIdx.y;
#pragma unroll
  for (int i = 0; i < 32; i += 8) {
    int r = r0 + ty + i, c = c0 + tx;
    tile[ty + i][tx] = in[(size_t)r * H + c];
  }
  __syncthreads();
#pragma unroll
  for (int i = 0; i < 32; i += 8) {
    int c = c0 + ty + i, r = r0 + tx;
    float v = tile[tx][ty + i];
    short t0 = f2bf(v);
    short t1 = f2bf(v - bf2f(t0));
    o0[doff + (size_t)c * H + r] = t0;
    o1[doff + (size_t)c * H + r] = t1;
  }
}

__global__ void k_bqkv(const float* __restrict__ bq, const float* __restrict__ bk,
                       const float* __restrict__ bv, float* __restrict__ bqkv) {
  int i = blockIdx.x * blockDim.x + threadIdx.x;
  if (i >= L * 3 * H) return;
  int l = i / (3 * H), j = i % (3 * H);
  float v = (j < H) ? bq[l * H + j] : (j < 2 * H) ? bk[l * H + j - H] : bv[l * H + j - 2 * H];
  bqkv[i] = v;
}

__global__ void k_ropetab(float* __restrict__ cosT, float* __restrict__ sinT) {
  int i = blockIdx.x * blockDim.x + threadIdx.x;
  if (i >= S * (HD / 2)) return;
  int s = i / 32, d = i % 32;
  float invf = powf(10000.f, -(2.f * d) / (float)HD);
  float ang = (float)s * invf;
  cosT[i] = cosf(ang);
  sinT[i] = sinf(ang);
}

__global__ void k_embed(const int* __restrict__ ids, const float* __restrict__ emb,
                        float* __restrict__ x) {
  int idx = blockIdx.x * blockDim.x + threadIdx.x;  // NTOK*(H/4)
  int row = idx / (H / 4), c4 = idx % (H / 4);
  if (row >= NTOK) return;
  int t = ids[row];
  ((f32x4*)(x + (size_t)row * H))[c4] = ((const f32x4*)(emb + (size_t)t * H))[c4];
}

// ---------------- layernorm with fused output formats ----------------
// OUT 1: split2 -> s0,s1           OUT 2: f32 of + split2 -> s0,s1
// OUT 3: f32 of + bf16 -> s0       OUT 4: bf16 -> s0
template <int OUT>
__global__ void k_layernorm(const float* __restrict__ x, const float* __restrict__ w,
                            const float* __restrict__ b, float* __restrict__ of,
                            short* __restrict__ s0, short* __restrict__ s1) {
  int row = blockIdx.x * (blockDim.x >> 6) + (threadIdx.x >> 6);
  int lane = threadIdx.x & 63;
  if (row >= NTOK) return;
  const float* xr = x + (size_t)row * H;
  float v[12], s = 0.f, s2s = 0.f;
#pragma unroll
  for (int j = 0; j < 12; j++) { float t = xr[lane + j * 64]; v[j] = t; s += t; s2s += t * t; }
#pragma unroll
  for (int off = 32; off; off >>= 1) { s += __shfl_xor(s, off); s2s += __shfl_xor(s2s, off); }
  float m = s / (float)H;
  float var = s2s / (float)H - m * m;
  float rs = 1.f / sqrtf(var + EPSLN);
#pragma unroll
  for (int j = 0; j < 12; j++) {
    int c = lane + j * 64;
    float val = (v[j] - m) * rs * w[c] + b[c];
    size_t idx = (size_t)row * H + c;
    if (OUT == 1) {
      short t0 = f2bf(val);
      s0[idx] = t0; s1[idx] = f2bf(val - bf2f(t0));
    } else if (OUT == 2) {
      of[idx] = val;
      short hi = f2bf(val);
      s0[idx] = hi; s1[idx] = f2bf(val - bf2f(hi));
    } else if (OUT == 3) {
      of[idx] = val;
      s0[idx] = f2bf(val);
    } else {
      s0[idx] = f2bf(val);
    }
  }
}

// ------- softmax over hi/lo bf16 scores, causal-prefix only, in place -------
// Row r (within its head) only has meaningful probability mass for columns
// < (r/128+1)*128 (PV's Keff cap never reads beyond). Masked-in-prefix cols
// reconstruct to -1e9 -> exp == +0 exactly (same as full version).
__global__ void k_softmax2(short* __restrict__ p0, short* __restrict__ p1) {
  int row = blockIdx.x * 4 + (threadIdx.x >> 6);  // B*NH*S rows
  int lane = threadIdx.x & 63;
  const int nb = ((row & (S - 1)) >> 7) + 1;      // 128-col chunks in prefix
  const size_t base = (size_t)row * S;
  float v[16];
  float mx = -3e38f;
#pragma unroll
  for (int c = 0; c < 8; ++c) {
    if (c < nb) {
      uint32_t u0 = *(const uint32_t*)(p0 + base + c * 128 + lane * 2);
      uint32_t u1 = *(const uint32_t*)(p1 + base + c * 128 + lane * 2);
      float a = bf2f((short)(u0 & 0xffff)) + bf2f((short)(u1 & 0xffff));
      float b = bf2f((short)(u0 >> 16)) + bf2f((short)(u1 >> 16));
      v[c * 2] = a; v[c * 2 + 1] = b;
      mx = fmaxf(mx, fmaxf(a, b));
    }
  }
#pragma unroll
  for (int off = 32; off; off >>= 1) mx = fmaxf(mx, __shfl_xor(mx, off));
  float sum = 0.f;
#pragma unroll
  for (int c = 0; c < 8; ++c) {
    if (c < nb) {
      float a = expf(v[c * 2] - mx);
      float b = expf(v[c * 2 + 1] - mx);
      v[c * 2] = a; v[c * 2 + 1] = b;
      sum += a + b;
    }
  }
#pragma unroll
  for (int off = 32; off; off >>= 1) sum += __shfl_xor(sum, off);
  float inv = 1.f / sum;
#pragma unroll
  for (int c = 0; c < 8; ++c) {
    if (c < nb) {
      float a = v[c * 2] * inv;
      float b = v[c * 2 + 1] * inv;
      short ah = f2bf(a), bh = f2bf(b);
      short al = f2bf(a - bf2f(ah)), bl = f2bf(b - bf2f(bh));
      *(uint32_t*)(p0 + base + c * 128 + lane * 2) =
          (uint32_t)(uint16_t)ah | ((uint32_t)(uint16_t)bh << 16);
      *(uint32_t*)(p1 + base + c * 128 + lane * 2) =
          (uint32_t)(uint16_t)al | ((uint32_t)(uint16_t)bl << 16);
    }
  }
}

// ---------------- router (f32 h input -> exact top-2) ----------------
__global__ void k_router(const float* __restrict__ h, const float* __restrict__ Wr,
                         const float* __restrict__ br, float* __restrict__ sel_w,
                         int* __restrict__ sel_e, int* __restrict__ counts) {
  int tok = blockIdx.x * (blockDim.x >> 6) + (threadIdx.x >> 6);
  int lane = threadIdx.x & 63;
  if (tok >= NTOK) return;
  const float* hr = h + (size_t)tok * H;
  float acc[8] = {0, 0, 0, 0, 0, 0, 0, 0};
  for (int i = lane; i < H; i += 64) {
    float hv = hr[i];
    const f32x4* w4 = (const f32x4*)(Wr + (size_t)i * E);
    f32x4 a = w4[0], b = w4[1];
    acc[0] += hv * a.x; acc[1] += hv * a.y; acc[2] += hv * a.z; acc[3] += hv * a.w;
    acc[4] += hv * b.x; acc[5] += hv * b.y; acc[6] += hv * b.z; acc[7] += hv * b.w;
  }
#pragma unroll
  for (int off = 32; off; off >>= 1)
#pragma unroll
    for (int e = 0; e < 8; e++) acc[e] += __shfl_xor(acc[e], off);
  if (lane == 0) {
    float lg[8], m = -3e38f;
#pragma unroll
    for (int e = 0; e < 8; e++) { lg[e] = acc[e] + br[e]; m = fmaxf(m, lg[e]); }
    float sum = 0.f;
#pragma unroll
    for (int e = 0; e < 8; e++) { lg[e] = expf(lg[e] - m); sum += lg[e]; }
    float inv = 1.f / sum;
#pragma unroll
    for (int e = 0; e < 8; e++) lg[e] *= inv;
    int i1 = 0;
#pragma unroll
    for (int e = 1; e < 8; e++) if (lg[e] > lg[i1]) i1 = e;
    int i2 = (i1 == 0) ? 1 : 0;
#pragma unroll
    for (int e = 0; e < 8; e++) if (e != i1 && lg[e] > lg[i2]) i2 = e;
    float p1 = lg[i1], p2 = lg[i2];
    float ws = p1 + p2 + 1e-9f;
    sel_e[tok * 2] = i1; sel_e[tok * 2 + 1] = i2;
    sel_w[tok * 2] = p1 / ws; sel_w[tok * 2 + 1] = p2 / ws;
    atomicAdd(counts + i1, 1);
    atomicAdd(counts + i2, 1);
  }
}

__global__ void k_offsets(const int* __restrict__ counts, int* __restrict__ offs) {
  if (threadIdx.x == 0) {
    int a = 0;
    for (int e = 0; e < E; e++) { offs[e] = a; a += counts[e]; }
    offs[E] = a;
  }
}

__global__ void k_scatter(const int* __restrict__ sel_e, const int* __restrict__ offs,
                          int* __restrict__ cursor, int* __restrict__ tok_list,
                          int* __restrict__ slot_of) {
  int tok = blockIdx.x * blockDim.x + threadIdx.x;
  if (tok >= NTOK) return;
  for (int k = 0; k < 2; k++) {
    int e = sel_e[tok * 2 + k];
    int pos = atomicAdd(cursor + e, 1);
    int g = offs[e] + pos;
    tok_list[g] = tok;
    slot_of[tok * 2 + k] = g;
  }
}

// ff = sum_k w_k * (oe[slot_k] + b2[e_k]); x += ff
__global__ void k_combine(const float* __restrict__ oe, const float* __restrict__ sel_w,
                          const int* __restrict__ slot_of, const int* __restrict__ sel_e,
                          const float* __restrict__ b2, float* __restrict__ x) {
  int idx = blockIdx.x * blockDim.x + threadIdx.x;  // NTOK*(H/4)
  if (idx >= NTOK * (H / 4)) return;
  int tok = idx / (H / 4), c4 = idx % (H / 4);
  float w0 = sel_w[tok * 2], w1 = sel_w[tok * 2 + 1];
  int s0 = slot_of[tok * 2], s1 = slot_of[tok * 2 + 1];
  int e0 = sel_e[tok * 2], e1 = sel_e[tok * 2 + 1];
  f32x4 a = ((const f32x4*)(oe + (size_t)s0 * H))[c4];
  f32x4 b = ((const f32x4*)(oe + (size_t)s1 * H))[c4];
  f32x4 ba = ((const f32x4*)(b2 + (size_t)e0 * H))[c4];
  f32x4 bb = ((const f32x4*)(b2 + (size_t)e1 * H))[c4];
  f32x4* xp = (f32x4*)(x + (size_t)tok * H) + c4;
  *xp = *xp + w0 * (a + ba) + w1 * (b + bb);
}

// ---------------- split-MFMA GEMM: C = (ΣA_s)·(ΣB_s)^T, products i+j<SP -----
// SP=2: 3 MFMAs/frag; SP=3: 6 MFMAs/frag.
// MODE 0: f32 out (+bias opt)   1: f32 out = res + acc + bias
// MODE 6: gelu(acc+bias) -> split2 bf16 (Cp,Cp2)
// MODE 7: acc*alpha + causal -> split2 bf16 (Cp,Cp2); tiles with tn>tm are
//         never read downstream (prefix softmax + PV K-cap) -> plain skip.
// MODE 8: acc -> split2 bf16 (Cp,Cp2); K capped at (tm+1)*128 (P beyond the
//         causal boundary is exactly +0 -> contribution exact 0).
// MODE 9: QKV fused: bias + RoPE + split2(q->Cp,Cp2, k->K0,K1) / split2(v)
template <int SP, int MODE, bool GATHER>
__global__ __launch_bounds__(256, 2) void k_bgemmS(
    const short* __restrict__ A0, const short* __restrict__ A1, const short* __restrict__ A2,
    long sAz, int lda,
    const short* __restrict__ B0, const short* __restrict__ B1, const short* __restrict__ B2,
    long sBz, int ldb,
    void* __restrict__ Cp, void* __restrict__ Cp2,
    short* __restrict__ K0, short* __restrict__ K1,
    short* __restrict__ V0, short* __restrict__ V1,
    const float* __restrict__ cT, const float* __restrict__ sT,
    int zdiv, long sChi, long sClo, int ldc,
    const float* __restrict__ res, const float* __restrict__ bias, long sBias,
    int M, int N, int K,
    const int* __restrict__ d_counts, const int* __restrict__ d_offs,
    const int* __restrict__ gidx, float alpha) {
  const int z = blockIdx.z;
  const int Meff = d_counts ? d_counts[z] : M;
  const int tm = blockIdx.y;
  if (tm * 128 >= Meff) return;
  const int tn = blockIdx.x;
  const int row_base = d_offs ? d_offs[z] : 0;

  if (MODE == 7 && tn > tm) return;  // never read downstream

  __shared__ short Ab[SP][128 * 32];
  __shared__ short Bb2[SP][128 * 32];

  const int tid = threadIdx.x;
  const int lane = tid & 63;
  const int w = tid >> 6;

  const int wr = (w >> 1) * 64;
  const int wc = (w & 1) * 64;
  const int r16 = lane & 15;
  const int kb4 = lane >> 4;
  const int q4 = lane >> 4;

  const short* APz[3];
  const short* BPz[3];
  APz[0] = A0 + (size_t)z * sAz;
  APz[1] = A1 + (size_t)z * sAz;
  APz[2] = (SP > 2) ? (A2 + (size_t)z * sAz) : APz[0];
  BPz[0] = B0 + (size_t)z * sBz;
  BPz[1] = B1 + (size_t)z * sBz;
  BPz[2] = (SP > 2) ? (B2 + (size_t)z * sBz) : BPz[0];

  size_t aOff[2], bOff[2];
#pragma unroll
  for (int i = 0; i < 2; ++i) {
    const int srow = i * 64 + (tid >> 2);
    const int kb = (tid & 3) ^ (srow & 3);  // pre-swizzled source (involution)
    int lrow = tm * 128 + srow;
    if (lrow > Meff - 1) lrow = Meff - 1;
    int ar = row_base + lrow;
    if (GATHER) ar = gidx[ar];
    aOff[i] = (size_t)ar * lda + kb * 8;
    int bcol = tn * 128 + srow;
    if (bcol > N - 1) bcol = N - 1;
    bOff[i] = (size_t)bcol * ldb + kb * 8;
  }

  f32x4 acc[4][4];
#pragma unroll
  for (int a = 0; a < 4; ++a)
#pragma unroll
    for (int b = 0; b < 4; ++b) acc[a][b] = {0.f, 0.f, 0.f, 0.f};

  const int swz = (kb4 ^ (r16 & 3)) * 8;
  int aoff[4], boff[4];
#pragma unroll
  for (int i = 0; i < 4; ++i) {
    aoff[i] = (wr + i * 16 + r16) * 32 + swz;
    boff[i] = (wc + i * 16 + r16) * 32 + swz;
  }

  // PV: keys beyond causal boundary have P == +0.0 exactly -> skip (exact).
  const int Keff = (MODE == 8) ? (((tm + 1) * 128 < K) ? (tm + 1) * 128 : K) : K;

  for (int k0 = 0; k0 < Keff; k0 += 32) {
#pragma unroll
    for (int s = 0; s < SP; ++s) {
      gload16(APz[s] + aOff[0], (char*)(&Ab[s][0]) + w * 1024);
      gload16(APz[s] + aOff[1], (char*)(&Ab[s][0]) + 4096 + w * 1024);
      gload16(BPz[s] + bOff[0], (char*)(&Bb2[s][0]) + w * 1024);
      gload16(BPz[s] + bOff[1], (char*)(&Bb2[s][0]) + 4096 + w * 1024);
    }
    aOff[0] += 32; aOff[1] += 32; bOff[0] += 32; bOff[1] += 32;
    __syncthreads();
    s16x8 af[SP][4], bf[SP][4];
#pragma unroll
    for (int s = 0; s < SP; ++s)
#pragma unroll
      for (int i = 0; i < 4; ++i) {
        af[s][i] = *(const s16x8*)(&Ab[s][aoff[i]]);
        bf[s][i] = *(const s16x8*)(&Bb2[s][boff[i]]);
      }
#pragma unroll
    for (int mi = 0; mi < 4; ++mi)
#pragma unroll
      for (int ni = 0; ni < 4; ++ni) {
        f32x4 a = acc[mi][ni];
#pragma unroll
        for (int si = 0; si < SP; ++si)
#pragma unroll
          for (int sj = 0; sj < SP - si; ++sj)
            a = __builtin_amdgcn_mfma_f32_16x16x32_bf16(af[si][mi], bf[sj][ni], a, 0, 0, 0);
        acc[mi][ni] = a;
      }
    __syncthreads();
  }

  const float* bz = bias ? (bias + (size_t)z * sBias) : nullptr;
  float bvv[4];
  int gco[4];
#pragma unroll
  for (int ni = 0; ni < 4; ++ni) {
    gco[ni] = tn * 128 + wc + ni * 16 + r16;
    bvv[ni] = (bz && gco[ni] < N) ? bz[gco[ni]] : 0.f;
  }

  if (MODE == 9) {
    // QKV fused epilogue: cols = [q(768) | k(768) | v(768)], heads of 64.
    const int sec_base = tn * 128 + wc;     // multiple of 64, aligned to sections
    const int sec = sec_base / H;           // 0=q, 1=k, 2=v
    const int hh = (sec_base % H) / HD;
#pragma unroll
    for (int mi = 0; mi < 4; ++mi) {
#pragma unroll
      for (int j = 0; j < 4; ++j) {
        const int row = tm * 128 + wr + mi * 16 + q4 * 4 + j;   // token
        const int ss = row & (S - 1);
        const long zz = (long)((row >> 10) * NHd + hh);
#pragma unroll
        for (int ni = 0; ni < 2; ++ni) {
          const int d = ni * 16 + r16;                          // 0..31
          float a1 = acc[mi][ni][j] + bvv[ni];
          float a2 = acc[mi][ni + 2][j] + bvv[ni + 2];
          if (sec < 2) {
            float cc = cT[ss * 32 + d], sn = sT[ss * 32 + d];
            float r1 = a1 * cc - a2 * sn;
            float r2 = a2 * cc + a1 * sn;
            const long bi = (zz * S + ss) * HD + d;
            short* d0 = (sec == 0) ? (short*)Cp : K0;
            short* d1 = (sec == 0) ? (short*)Cp2 : K1;
            short t0 = f2bf(r1);
            d0[bi] = t0; d1[bi] = f2bf(r1 - bf2f(t0));
            t0 = f2bf(r2);
            d0[bi + 32] = t0; d1[bi + 32] = f2bf(r2 - bf2f(t0));
          } else {
            const long vb1 = zz * HD * S + (long)d * S + ss;
            short hv = f2bf(a1);
            V0[vb1] = hv; V1[vb1] = f2bf(a1 - bf2f(hv));
            const long vb2 = vb1 + 32L * S;
            hv = f2bf(a2);
            V0[vb2] = hv; V1[vb2] = f2bf(a2 - bf2f(hv));
          }
        }
      }
    }
    return;
  }

  const long out_off = (long)(z / zdiv) * sChi + (long)(z % zdiv) * sClo;
#pragma unroll
  for (int mi = 0; mi < 4; ++mi) {
#pragma unroll
    for (int j = 0; j < 4; ++j) {
      const int lrow = tm * 128 + wr + mi * 16 + q4 * 4 + j;
      if (lrow >= Meff) continue;
      const long rbase = out_off + (long)(row_base + lrow) * ldc;
#pragma unroll
      for (int ni = 0; ni < 4; ++ni) {
        if (gco[ni] >= N) continue;
        const float v = acc[mi][ni][j];
        const long idx = rbase + gco[ni];
        if (MODE == 0) {
          ((float*)Cp)[idx] = v + bvv[ni];
        } else if (MODE == 1) {
          ((float*)Cp)[idx] = res[idx] + v + bvv[ni];
        } else if (MODE == 6) {
          float g = gelu1(v + bvv[ni]);
          short hi = f2bf(g);
          ((short*)Cp)[idx] = hi;
          ((short*)Cp2)[idx] = f2bf(g - bf2f(hi));
        } else if (MODE == 7) {
          float g = v * alpha + ((gco[ni] > lrow) ? -1e9f : 0.f);
          short hi = f2bf(g);
          ((short*)Cp)[idx] = hi;
          ((short*)Cp2)[idx] = f2bf(g - bf2f(hi));
        } else if (MODE == 8) {
          float g = v + bvv[ni];
          short t0 = f2bf(g);
          ((short*)Cp)[idx] = t0;
          ((short*)Cp2)[idx] = f2bf(g - bf2f(t0));
        }
      }
    }
  }
}

template <int SP, int MODE, bool GATHER>
static void bgemmS(hipStream_t st, const short* A0, const short* A1, const short* A2, long sAz,
                   int lda, const short* B0, const short* B1, const short* B2, long sBz,
                   int ldb, void* C, void* C2, int zdiv, long sChi, long sClo,
                   int ldc, const float* res, const float* bias, long sBias, int M, int N,
                   int K, int nz, const int* cnts, const int* offs_, const int* gat,
                   float alpha, short* K0 = nullptr, short* K1 = nullptr,
                   short* V0 = nullptr, short* V1 = nullptr, const float* cT = nullptr,
                   const float* sT = nullptr) {
  dim3 g((N + 127) / 128, (M + 127) / 128, nz);
  k_bgemmS<SP, MODE, GATHER><<<g, 256, 0, st>>>(A0, A1, A2, sAz, lda, B0, B1, B2, sBz, ldb, C,
                                                C2, K0, K1, V0, V1, cT, sT, zdiv, sChi,
                                                sClo, ldc, res, bias, sBias, M, N, K, cnts,
                                                offs_, gat, alpha);
}

// ---------------- plain bf16 MFMA GEMM, BK=64 (l1 MoE + logits) --------------
// R10-proven structure: single-buffered, 32 KB LDS, XOR-swizzled staging.
// MODE 0: f32 out (+bias opt)   4: bf16 out = gelu(acc + bias)
// NSWZ: N-major + bijective XCD-chunk swizzle (B-tile L2 locality).
template <int MODE, bool GATHER, bool NSWZ>
__global__ __launch_bounds__(256, 2) void k_bgemm(
    const short* __restrict__ A, long sAz, int lda,
    const short* __restrict__ Bt, long sBz, int ldb,
    void* __restrict__ Cp, int zdiv, long sChi, long sClo, int ldc,
    const float* __restrict__ bias, long sBias,
    int M, int N, int K,
    const int* __restrict__ d_counts, const int* __restrict__ d_offs,
    const int* __restrict__ gidx) {
  const int z = blockIdx.z;
  const int Meff = d_counts ? d_counts[z] : M;
  int tm, tn;
  if (NSWZ) {
    const int bid = blockIdx.y * gridDim.x + blockIdx.x;
    const int nwg = gridDim.x * gridDim.y;
    const int q = nwg >> 3, r = nwg & 7;
    const int xcd = bid & 7, ix = bid >> 3;
    const int wg = (xcd < r) ? (xcd * (q + 1) + ix) : (r * (q + 1) + (xcd - r) * q + ix);
    tn = wg / gridDim.y;   // N-major: consecutive wg share tn
    tm = wg % gridDim.y;
  } else {
    tm = blockIdx.y;
    tn = blockIdx.x;
  }
  if (tm * 128 >= Meff) return;
  const int row_base = d_offs ? d_offs[z] : 0;

  __shared__ short Abuf[128 * 64];   // 16 KB
  __shared__ short Bbuf[128 * 64];   // 16 KB

  const int tid = threadIdx.x;
  const int lane = tid & 63;
  const int w = tid >> 6;

  const short* Az = A + (size_t)z * sAz;
  const short* Bz = Bt + (size_t)z * sBz;

  // staging: chunk c = w*4+i covers LDS rows c*8..c*8+7; lane -> row c*8+(lane>>3),
  // k-unit lane&7; source k pre-swizzled by (row&7)^unit (involution, rule #21).
  const int swzS = ((lane >> 3) ^ (lane & 7)) * 8;
  const short* aSrc[4];
  const short* bSrc[4];
#pragma unroll
  for (int i = 0; i < 4; ++i) {
    const int rin = (w * 4 + i) * 8 + (lane >> 3);  // 0..127
    int lrow = tm * 128 + rin;
    if (lrow > Meff - 1) lrow = Meff - 1;
    int ar = row_base + lrow;
    if (GATHER) ar = gidx[ar];
    aSrc[i] = Az + (size_t)ar * lda + swzS;
    int bcol = tn * 128 + rin;
    if (bcol > N - 1) bcol = N - 1;
    bSrc[i] = Bz + (size_t)bcol * ldb + swzS;
  }

  f32x4 acc[4][4];
#pragma unroll
  for (int a = 0; a < 4; ++a)
#pragma unroll
    for (int b = 0; b < 4; ++b) acc[a][b] = {0.f, 0.f, 0.f, 0.f};

  const int wr = (w >> 1) * 64;
  const int wc = (w & 1) * 64;
  const int r16 = lane & 15;
  const int kb4 = lane >> 4;
  int aoff[4][2], boff[4][2];
#pragma unroll
  for (int i = 0; i < 4; ++i) {
#pragma unroll
    for (int kw = 0; kw < 2; ++kw) {
      const int sw = ((r16 & 7) ^ (kw * 4 + kb4)) * 8;
      aoff[i][kw] = (wr + i * 16 + r16) * 64 + sw;
      boff[i][kw] = (wc + i * 16 + r16) * 64 + sw;
    }
  }

  for (int k0 = 0; k0 < K; k0 += 64) {
#pragma unroll
    for (int i = 0; i < 4; ++i) gload16(aSrc[i], (char*)Abuf + (w * 4 + i) * 1024);
#pragma unroll
    for (int i = 0; i < 4; ++i) gload16(bSrc[i], (char*)Bbuf + (w * 4 + i) * 1024);
#pragma unroll
    for (int i = 0; i < 4; ++i) { aSrc[i] += 64; bSrc[i] += 64; }
    __syncthreads();
#pragma unroll
    for (int kw = 0; kw < 2; ++kw) {
      s16x8 af[4], bf[4];
#pragma unroll
      for (int i = 0; i < 4; ++i) {
        af[i] = *(const s16x8*)(Abuf + aoff[i][kw]);
        bf[i] = *(const s16x8*)(Bbuf + boff[i][kw]);
      }
#pragma unroll
      for (int mi = 0; mi < 4; ++mi)
#pragma unroll
        for (int ni = 0; ni < 4; ++ni)
          acc[mi][ni] =
              __builtin_amdgcn_mfma_f32_16x16x32_bf16(af[mi], bf[ni], acc[mi][ni], 0, 0, 0);
    }
    __syncthreads();
  }

  const long out_off = (long)(z / zdiv) * sChi + (long)(z % zdiv) * sClo;
  const float* bz = bias ? (bias + (size_t)z * sBias) : nullptr;
  const int q4 = lane >> 4;
  float bvv[4];
  int gco[4];
#pragma unroll
  for (int ni = 0; ni < 4; ++ni) {
    gco[ni] = tn * 128 + wc + ni * 16 + r16;
    bvv[ni] = (bz && gco[ni] < N) ? bz[gco[ni]] : 0.f;
  }
#pragma unroll
  for (int mi = 0; mi < 4; ++mi) {
#pragma unroll
    for (int j = 0; j < 4; ++j) {
      const int lrow = tm * 128 + wr + mi * 16 + q4 * 4 + j;
      if (lrow >= Meff) continue;
      const long rbase = out_off + (row_base + lrow) * (long)ldc;
#pragma unroll
      for (int ni = 0; ni < 4; ++ni) {
        if (gco[ni] >= N) continue;
        const float v = acc[mi][ni][j];
        if (MODE == 0) {
          ((float*)Cp)[rbase + gco[ni]] = v + bvv[ni];
        } else if (MODE == 4) {
          float g = v + bvv[ni];
          ((short*)Cp)[rbase + gco[ni]] = f2bf(gelu1(g));
        }
      }
    }
  }
}

template <int MODE, bool GATHER, bool NSWZ>
static void bgemm(hipStream_t st, const short* A, long sAz, int lda, const short* Bt, long sBz,
                  int ldb, void* C, int zdiv, long sChi, long sClo, int ldc, const float* bias,
                  long sBias, int M, int N, int K, int nz, const int* cnts, const int* offs_,
                  const int* gat) {
  dim3 g((N + 127) / 128, (M + 127) / 128, nz);
  k_bgemm<MODE, GATHER, NSWZ><<<g, 256, 0, st>>>(A, sAz, lda, Bt, sBz, ldb, C, zdiv, sChi,
                                                 sClo, ldc, bias, sBias, M, N, K, cnts, offs_,
                                                 gat);
}

// ---------------- launch ----------------
extern "C" void kernel_launch(void* const* d_in, const int* in_sizes, int n_in, void* d_out,
                              int out_size, void* d_ws, size_t ws_size, hipStream_t stream) {
  (void)in_sizes; (void)n_in; (void)out_size; (void)ws_size;
  const int*   ids  = (const int*)d_in[0];
  const float* emb  = (const float*)d_in[1];
  const float* ln1w = (const float*)d_in[2];
  const float* ln1b = (const float*)d_in[3];
  const float* ln2w = (const float*)d_in[4];
  const float* ln2b = (const float*)d_in[5];
  const float* lnfw = (const float*)d_in[6];
  const float* lnfb = (const float*)d_in[7];
  const float* Wq = (const float*)d_in[8];
  const float* bq = (const float*)d_in[9];
  const float* Wk = (const float*)d_in[10];
  const float* bk = (const float*)d_in[11];
  const float* Wv = (const float*)d_in[12];
  const float* bv = (const float*)d_in[13];
  const float* Wo = (const float*)d_in[14];
  const float* bo = (const float*)d_in[15];
  const float* Wr = (const float*)d_in[16];
  const float* br = (const float*)d_in[17];
  const float* W1 = (const float*)d_in[18];
  const float* b1 = (const float*)d_in[19];
  const float* W2 = (const float*)d_in[20];
  const float* b2 = (const float*)d_in[21];
  float* out = (float*)d_out;

  char* p = (char*)d_ws;
  auto alloc = [&](size_t bytes) {
    char* r = p;
    p += (bytes + 255) & ~(size_t)255;
    return r;
  };
  short* embB = (short*)alloc((size_t)V * H * 2);               // 77.2 MB
  // big region (100.7 MB), time-shared: attention [p0|p1] vs MoE [R_hi|R_lo]
  char* big = alloc((size_t)Bb * NHd * S * S * 2 * 2);
  short* p0   = (short*)big;
  short* p1   = p0 + (size_t)Bb * NHd * S * S;
  short* R_hi = (short*)big;
  short* R_lo = R_hi + (size_t)E * F * H;
  short* Wb0 = (short*)alloc((size_t)3 * H * H * 2);            // QKV W^T 2-splits
  short* Wb1 = (short*)alloc((size_t)3 * H * H * 2);
  short* Wo0 = (short*)alloc((size_t)H * H * 2);                // Wo^T 2-splits
  short* Wo1 = (short*)alloc((size_t)H * H * 2);
  float* bqkv = (float*)alloc((size_t)L * 3 * H * 4);
  float* cosT = (float*)alloc((size_t)S * 32 * 4);
  float* sinT = (float*)alloc((size_t)S * 32 * 4);
  float* x    = (float*)alloc((size_t)NTOK * H * 4);
  float* hbuf = (float*)alloc((size_t)NTOK * H * 4);
  short* xb   = (short*)alloc((size_t)NTOK * H * 2);
  short* xb2  = (short*)alloc((size_t)NTOK * H * 2);
  short* h_hi = (short*)alloc((size_t)NTOK * H * 2);
  short* h_lo = (short*)alloc((size_t)NTOK * H * 2);
  short* h30  = (short*)alloc((size_t)NTOK * H * 2);
  short* h31  = (short*)alloc((size_t)NTOK * H * 2);
  short* q30  = (short*)alloc((size_t)NTOK * H * 2);
  short* q31  = (short*)alloc((size_t)NTOK * H * 2);
  short* k30  = (short*)alloc((size_t)NTOK * H * 2);
  short* k31  = (short*)alloc((size_t)NTOK * H * 2);
  short* v20  = (short*)alloc((size_t)NTOK * H * 2);
  short* v21  = (short*)alloc((size_t)NTOK * H * 2);
  short* o30  = (short*)alloc((size_t)NTOK * H * 2);
  short* o31  = (short*)alloc((size_t)NTOK * H * 2);
  // union region (63.1 MB): act_hi+act_lo (l0) / act_b (l1) + oe
  char* uni = alloc((size_t)NSLOT * F * 4 + (size_t)NSLOT * H * 4);
  short* act_hi = (short*)uni;
  short* act_lo = (short*)(uni + (size_t)NSLOT * F * 2);
  short* act_b  = (short*)uni;
  float* oe     = (float*)(uni + (size_t)NSLOT * F * 4);
  int* counts  = (int*)alloc(2 * E * 4);
  int* cursor  = counts + E;
  int* offs    = (int*)alloc((E + 1) * 4);
  int* sel_e   = (int*)alloc((size_t)NTOK * 2 * 4);
  float* sel_w = (float*)alloc((size_t)NTOK * 2 * 4);
  int* slot_of = (int*)alloc((size_t)NTOK * 2 * 4);
  int* tok_lst = (int*)alloc((size_t)NSLOT * 4);

  // ---- prologue ----
  long nEmb4 = (long)V * H / 4;
  k_f32_to_bf16<<<(nEmb4 + 255) / 256, 256, 0, stream>>>(emb, embB, nEmb4);
  k_bqkv<<<(L * 3 * H + 255) / 256, 256, 0, stream>>>(bq, bk, bv, bqkv);
  k_ropetab<<<(S * 32 + 255) / 256, 256, 0, stream>>>(cosT, sinT);
  k_embed<<<(NTOK * (H / 4) + 255) / 256, 256, 0, stream>>>(ids, emb, x);

  dim3 tb(32, 8);
  const dim3 tHH(H / 32, H / 32, 1);

  for (int l = 0; l < L; l++) {
    // --- attention (bf16x3 split-MFMA; upstream of routers) ---
    k_layernorm<1><<<NTOK / 4, 256, 0, stream>>>(x, ln1w + l * H, ln1b + l * H, nullptr, h30,
                                                 h31);
    k_wqkv_t2<<<dim3(H / 32, H / 32, 3), tb, 0, stream>>>(
        Wq + (size_t)l * H * H, Wk + (size_t)l * H * H, Wv + (size_t)l * H * H, Wb0, Wb1);
    // QKV fused with bias+RoPE+splits (MODE 9)
    bgemmS<2, 9, false>(stream, h30, h31, nullptr, 0, H, Wb0, Wb1, nullptr, 0, H, q30, q31,
                        1, 0, 0, 0, nullptr, bqkv + l * 3 * H, 0, NTOK, 3 * H, H, 1, nullptr,
                        nullptr, nullptr, 1.f, k30, k31, v20, v21, cosT, sinT);
    // QK^T: scale+causal -> hi/lo bf16 scores (fully-masked tiles skipped)
    bgemmS<2, 7, false>(stream, q30, q31, nullptr, (long)S * HD, HD, k30, k31, nullptr,
                        (long)S * HD, HD, p0, p1, 1, (long)S * S, 0, S, nullptr, nullptr, 0,
                        S, S, HD, Bb * NHd, nullptr, nullptr, nullptr, 0.125f);
    k_softmax2<<<(Bb * NHd * S) / 4, 256, 0, stream>>>(p0, p1);
    // PV -> o split2 (MODE 8; K capped at causal boundary)
    bgemmS<2, 8, false>(stream, p0, p1, nullptr, (long)S * S, S, v20, v21, nullptr,
                        (long)HD * S, S, o30, o31, NHd, (long)S * H, HD, H, nullptr,
                        nullptr, 0, S, HD, S, Bb * NHd, nullptr, nullptr, nullptr, 1.f);
    // Wo: x += o @ Wo + bo
    k_transpose_split<<<tHH, tb, 0, stream>>>(Wo + (size_t)l * H * H, Wo0, Wo1, H, H, 0, 0);
    bgemmS<2, 1, false>(stream, o30, o31, nullptr, 0, H, Wo0, Wo1, nullptr, 0, H, x, nullptr,
                        1, 0, 0, H, x, bo + l * H, 0, NTOK, H, H, 1, nullptr, nullptr, nullptr,
                        1.f);

    // --- MoE ---
    if (l == 0)
      k_layernorm<2><<<NTOK / 4, 256, 0, stream>>>(x, ln2w + l * H, ln2b + l * H, hbuf, h_hi,
                                                   h_lo);
    else
      k_layernorm<3><<<NTOK / 4, 256, 0, stream>>>(x, ln2w + l * H, ln2b + l * H, hbuf, xb2,
                                                   nullptr);
    hipMemsetAsync(counts, 0, 2 * E * sizeof(int), stream);
    k_router<<<NTOK / 4, 256, 0, stream>>>(hbuf, Wr + (size_t)l * H * E, br + l * E, sel_w,
                                           sel_e, counts);
    k_offsets<<<1, 64, 0, stream>>>(counts, offs);
    k_scatter<<<(NTOK + 255) / 256, 256, 0, stream>>>(sel_e, offs, cursor, tok_lst, slot_of);
    if (l == 0) {
      // bf16x3 split MFMA experts (proven path; p0/p1 dead -> R region free)
      k_transpose_split<<<dim3(F / 32, H / 32, E), tb, 0, stream>>>(
          W1, R_hi, R_lo, H, F, (long)H * F, (long)F * H);
      bgemmS<2, 6, true>(stream, h_hi, h_lo, nullptr, 0, H, R_hi, R_lo, nullptr, (long)F * H,
                         H, act_hi, act_lo, 1, 0, 0, F, nullptr, b1, F, NSLOT, F, H,
                         E, counts, offs, tok_lst, 1.f);
      k_transpose_split<<<dim3(H / 32, F / 32, E), tb, 0, stream>>>(
          W2, R_hi, R_lo, F, H, (long)F * H, (long)H * F);
      bgemmS<2, 0, false>(stream, act_hi, act_lo, nullptr, 0, F, R_hi, R_lo, nullptr,
                          (long)H * F, F, oe, nullptr, 1, 0, 0, H, nullptr, nullptr,
                          0, NSLOT, H, F, E, counts, offs, nullptr, 1.f);
      k_combine<<<(NTOK * (H / 4) + 255) / 256, 256, 0, stream>>>(oe, sel_w, slot_of, sel_e,
                                                                  b2, x);
    } else {
      // plain bf16 MFMA experts (128-tile BK=64); stage l1 weights
      k_transpose_bf16<<<dim3(F / 32, H / 32, E), tb, 0, stream>>>(
          W1 + (size_t)1 * E * H * F, R_hi, H, F, (long)H * F, (long)F * H);
      k_transpose_bf16<<<dim3(H / 32, F / 32, E), tb, 0, stream>>>(
          W2 + (size_t)1 * E * F * H, R_lo, F, H, (long)F * H, (long)H * F);
      bgemm<4, true, false>(stream, xb2, 0, H, R_hi, (long)F * H, H, act_b, 1, 0, 0, F,
                            b1 + (size_t)l * E * F, F, NSLOT, F, H, E, counts, offs, tok_lst);
      bgemm<0, false, false>(stream, act_b, 0, F, R_lo, (long)H * F, F, oe, 1, 0, 0, H,
                             nullptr, 0, NSLOT, H, F, E, counts, offs, nullptr);
      k_combine<<<(NTOK * (H / 4) + 255) / 256, 256, 0, stream>>>(oe, sel_w, slot_of, sel_e,
                                                                  b2 + (size_t)l * E * H, x);
    }
  }

  // --- final LN + tied logits (BK=64 bf16 MFMA, XCD-chunked N-major) ---
  k_layernorm<4><<<NTOK / 4, 256, 0, stream>>>(x, lnfw, lnfb, nullptr, xb, nullptr);
  bgemm<0, false, true>(stream, xb, 0, H, embB, 0, H, out, 1, 0, 0, V, nullptr, 0, NTOK, V, H,
                        1, nullptr, nullptr, nullptr);
}